// Round 1
// baseline (10968.951 us; speedup 1.0000x reference)
//
#include <hip/hip_runtime.h>
#include <math.h>

// ---- problem constants ----
#define BB 8
#define NN 2048
#define PSZ 32
#define PP 64
#define DD 1024
#define MLPD 2048
#define DEPTH_ 6
#define HH 8
#define DHH 64
#define INNER_ 512
#define KK 20
#define TOK 65
#define EPSF 1e-5f

#define GEMM_ACC 1
#define GEMM_GELU 2

// x [B,N,3] -> pts [B,3,N]
__global__ void transpose_x_kernel(const float* __restrict__ x, float* __restrict__ pts) {
    int gid = blockIdx.x * blockDim.x + threadIdx.x;
    if (gid >= BB * NN * 3) return;
    int c = gid % 3; int n = (gid / 3) % NN; int b = gid / (3 * NN);
    pts[(b * 3 + c) * NN + n] = x[gid];
}

// xx[b,n] = sum_c x[b,c,n]^2   (x has per-batch channel stride bs)
__global__ void sqnorm_kernel(const float* __restrict__ x, int bs, int C, float* __restrict__ xx) {
    int gid = blockIdx.x * blockDim.x + threadIdx.x;
    if (gid >= BB * NN) return;
    int n = gid % NN; int b = gid / NN;
    const float* xp = x + b * bs + n;
    float s = 0.f;
    for (int c = 0; c < C; ++c) { float v = xp[c * NN]; s += v * v; }
    xx[gid] = s;
}

// one block per (b,n): dist row in LDS, 20 argmax rounds (ties -> smallest idx)
__global__ __launch_bounds__(256) void knn_kernel(const float* __restrict__ x, int bs, int C,
                                                  const float* __restrict__ xx, int* __restrict__ idx) {
    __shared__ float sdist[NN];
    __shared__ float sc[128];
    __shared__ float rval[256];
    __shared__ int   ridx[256];
    int bn = blockIdx.x;
    int b = bn / NN, n = bn % NN;
    int tid = threadIdx.x;
    for (int c = tid; c < C; c += 256) sc[c] = x[b * bs + c * NN + n];
    __syncthreads();
    float xn = xx[bn];
    for (int mi = 0; mi < NN / 256; ++mi) {
        int m = tid + mi * 256;
        float acc = 0.f;
        const float* xp = x + b * bs + m;
        for (int c = 0; c < C; ++c) acc += sc[c] * xp[c * NN];
        sdist[m] = 2.f * acc - xn - xx[b * NN + m];
    }
    __syncthreads();
    for (int kk = 0; kk < KK; ++kk) {
        float bv = -INFINITY; int bi = NN;
        for (int mi = 0; mi < NN / 256; ++mi) {
            int m = tid + mi * 256;
            float v = sdist[m];
            if (v > bv) { bv = v; bi = m; }   // within-thread m increases -> keeps smallest idx on tie
        }
        rval[tid] = bv; ridx[tid] = bi;
        __syncthreads();
        for (int s = 128; s > 0; s >>= 1) {
            if (tid < s) {
                float ov = rval[tid + s]; int oi = ridx[tid + s];
                if (ov > rval[tid] || (ov == rval[tid] && oi < ridx[tid])) { rval[tid] = ov; ridx[tid] = oi; }
            }
            __syncthreads();
        }
        if (tid == 0) { idx[bn * KK + kk] = ridx[0]; sdist[ridx[0]] = -INFINITY; }
        __syncthreads();
    }
}

// p[b,n,o] = sum_c x[b,c,n]*w[o,c]; q[b,n,o] = sum_c x[b,c,n]*(w[o,C+c]-w[o,c])
__global__ void pq_kernel(const float* __restrict__ x, int bs, int C,
                          const float* __restrict__ w, int O,
                          float* __restrict__ p, float* __restrict__ q) {
    int gid = blockIdx.x * blockDim.x + threadIdx.x;
    if (gid >= BB * NN * O) return;
    int o = gid % O; int n = (gid / O) % NN; int b = gid / (O * NN);
    const float* wr = w + o * 2 * C;
    const float* xc = x + b * bs + n;
    float ps = 0.f, qs = 0.f;
    for (int c = 0; c < C; ++c) {
        float xv = xc[c * NN];
        float wa = wr[c], wb = wr[C + c];
        ps += xv * wa; qs += xv * (wb - wa);
    }
    p[gid] = ps; q[gid] = qs;
}

__global__ void zero_stats_kernel(double* __restrict__ s1, double* __restrict__ s2) {
    int t = blockIdx.x * blockDim.x + threadIdx.x;
    if (t < 1024) { s1[t] = 0.0; s2[t] = 0.0; }
}

// BN stats over (b,n,k) per output channel, y = p[b,j,o] + q[b,n,o]
__global__ __launch_bounds__(256) void edge_stats_kernel(const float* __restrict__ p, const float* __restrict__ q,
                                                         const int* __restrict__ idx, int O,
                                                         double* __restrict__ gsum, double* __restrict__ gsumsq) {
    int tid = threadIdx.x;
    int o = tid % O;
    int grp = tid / O;
    int ngrp = 256 / O;
    int rows_per_blk = (BB * NN) / gridDim.x;
    int r0 = blockIdx.x * rows_per_blk;
    double s = 0.0, ss = 0.0;
    for (int r = r0 + grp; r < r0 + rows_per_blk; r += ngrp) {
        int b = r / NN;
        float qv = q[r * O + o];
        for (int k = 0; k < KK; ++k) {
            int j = idx[r * KK + k];
            float v = p[(b * NN + j) * O + o] + qv;
            s += v; ss += (double)v * v;
        }
    }
    atomicAdd(&gsum[o], s);
    atomicAdd(&gsumsq[o], ss);
}

__global__ void bn_finalize_kernel(const double* __restrict__ gsum, const double* __restrict__ gsumsq,
                                   const float* __restrict__ g, const float* __restrict__ bb, int O, double cnt,
                                   float* __restrict__ scale, float* __restrict__ shift) {
    int o = blockIdx.x * blockDim.x + threadIdx.x;
    if (o >= O) return;
    double mean = gsum[o] / cnt;
    double var = gsumsq[o] / cnt - mean * mean;
    float inv = rsqrtf((float)var + EPSF);
    float sc = g[o] * inv;
    scale[o] = sc;
    shift[o] = bb[o] - (float)mean * sc;
}

// out[b,o,n] = max_k lrelu((p[b,j,o]+q[b,n,o])*scale+shift); out has per-batch channel stride obs
__global__ void edge_out_kernel(const float* __restrict__ p, const float* __restrict__ q,
                                const int* __restrict__ idx, int O,
                                const float* __restrict__ scale, const float* __restrict__ shift,
                                float* __restrict__ out, int obs) {
    int gid = blockIdx.x * blockDim.x + threadIdx.x;
    if (gid >= BB * NN * O) return;
    int o = gid % O; int n = (gid / O) % NN; int b = gid / (O * NN);
    int r = b * NN + n;
    float qv = q[r * O + o];
    float sc = scale[o], sh = shift[o];
    float m = -INFINITY;
    for (int k = 0; k < KK; ++k) {
        int j = idx[r * KK + k];
        float v = (p[(b * NN + j) * O + o] + qv) * sc + sh;
        v = (v >= 0.f) ? v : 0.2f * v;
        m = fmaxf(m, v);
    }
    out[b * obs + o * NN + n] = m;
}

// generic fp32 GEMM: out[M,N] = A[M,K]·B[K,N] (+bias per col, optional GELU, optional accumulate)
// 64x64 block tile, 16 k-step, 4x4 per thread. K must be a multiple of 16 (true for all call sites).
__global__ __launch_bounds__(256) void gemm_kernel(const float* __restrict__ A, const float* __restrict__ Bm,
                                                   const float* __restrict__ bias, float* __restrict__ out,
                                                   int M, int Kd, int Nd, long sA, long sB, long sO, int flags) {
    __shared__ float As[16][65];
    __shared__ float Bs[16][64];
    const float* Ab = A + (long)blockIdx.z * sA;
    const float* Bb = Bm + (long)blockIdx.z * sB;
    float* Ob = out + (long)blockIdx.z * sO;
    int row0 = blockIdx.y * 64, col0 = blockIdx.x * 64;
    int tid = threadIdx.x;
    int ty = tid / 16, tx = tid % 16;
    float acc[4][4] = {};
    for (int k0 = 0; k0 < Kd; k0 += 16) {
        for (int i = 0; i < 4; ++i) {
            int li = tid + i * 256;
            int m = li / 16, kk = li % 16;
            int r = row0 + m;
            As[kk][m] = (r < M) ? Ab[(long)r * Kd + k0 + kk] : 0.f;
        }
        for (int i = 0; i < 4; ++i) {
            int li = tid + i * 256;
            int kk = li / 64, n = li % 64;
            int c = col0 + n;
            Bs[kk][n] = (c < Nd) ? Bb[(long)(k0 + kk) * Nd + c] : 0.f;
        }
        __syncthreads();
        for (int kk = 0; kk < 16; ++kk) {
            float a[4], bv[4];
            for (int i = 0; i < 4; ++i) a[i] = As[kk][ty * 4 + i];
            for (int j = 0; j < 4; ++j) bv[j] = Bs[kk][tx * 4 + j];
            for (int i = 0; i < 4; ++i)
                for (int j = 0; j < 4; ++j)
                    acc[i][j] += a[i] * bv[j];
        }
        __syncthreads();
    }
    for (int i = 0; i < 4; ++i) {
        int r = row0 + ty * 4 + i;
        if (r >= M) continue;
        for (int j = 0; j < 4; ++j) {
            int c = col0 + tx * 4 + j;
            if (c >= Nd) continue;
            float v = acc[i][j];
            if (bias) v += bias[c];
            if (flags & GEMM_GELU) v = 0.5f * v * (1.f + erff(v * 0.70710678118654752f));
            long oidx = (long)r * Nd + c;
            if (flags & GEMM_ACC) Ob[oidx] += v; else Ob[oidx] = v;
        }
    }
}

// BN5 stats: per channel d over (b,n) of y5[b,d,n]; writes scale/shift directly
__global__ __launch_bounds__(256) void bn5_stats_kernel(const float* __restrict__ y5, const float* __restrict__ g,
                                                        const float* __restrict__ bb,
                                                        float* __restrict__ scale, float* __restrict__ shift) {
    __shared__ double ssum[256], ssq[256];
    int d = blockIdx.x;
    int tid = threadIdx.x;
    double s = 0.0, sq = 0.0;
    for (int b = 0; b < BB; ++b) {
        const float* row = y5 + ((long)b * DD + d) * NN;
        for (int n = tid; n < NN; n += 256) { float v = row[n]; s += v; sq += (double)v * v; }
    }
    ssum[tid] = s; ssq[tid] = sq;
    __syncthreads();
    for (int st = 128; st > 0; st >>= 1) {
        if (tid < st) { ssum[tid] += ssum[tid + st]; ssq[tid] += ssq[tid + st]; }
        __syncthreads();
    }
    if (tid == 0) {
        double cnt = (double)BB * NN;
        double mean = ssum[0] / cnt;
        double var = ssq[0] / cnt - mean * mean;
        float inv = rsqrtf((float)var + EPSF);
        float sc = g[d] * inv;
        scale[d] = sc;
        shift[d] = bb[d] - (float)mean * sc;
    }
}

// tokens: t[b,0,:]=cls; t[b,1+p,d] = max over 32 pts of lrelu(y5*scale+shift)
__global__ void pool_kernel(const float* __restrict__ y5, const float* __restrict__ scale,
                            const float* __restrict__ shift, const float* __restrict__ cls,
                            float* __restrict__ t) {
    int gid = blockIdx.x * blockDim.x + threadIdx.x;
    if (gid >= BB * TOK * DD) return;
    int d = gid % DD; int l = (gid / DD) % TOK; int b = gid / (DD * TOK);
    float v;
    if (l == 0) {
        v = cls[d];
    } else {
        int pp = l - 1;
        const float* row = y5 + ((long)b * DD + d) * NN + pp * PSZ;
        float sc = scale[d], sh = shift[d];
        float m = -INFINITY;
        for (int i = 0; i < PSZ; ++i) {
            float u = row[i] * sc + sh;
            u = (u >= 0.f) ? u : 0.2f * u;
            m = fmaxf(m, u);
        }
        v = m;
    }
    t[gid] = v;
}

// per-token LayerNorm; if addpos: t += pos first (written back), then normalize
__global__ __launch_bounds__(256) void ln_kernel(float* __restrict__ t, const float* __restrict__ pos,
                                                 const float* __restrict__ g, const float* __restrict__ bb,
                                                 float* __restrict__ hn, int addpos) {
    __shared__ double s1[256], s2[256];
    long r = blockIdx.x;
    int tid = threadIdx.x;
    float vals[4];
    double s = 0.0, sq = 0.0;
    for (int i = 0; i < 4; ++i) {
        int d = tid + i * 256;
        float v = t[r * DD + d];
        if (addpos) { v += pos[r * DD + d]; t[r * DD + d] = v; }
        vals[i] = v; s += v; sq += (double)v * v;
    }
    s1[tid] = s; s2[tid] = sq;
    __syncthreads();
    for (int st = 128; st > 0; st >>= 1) {
        if (tid < st) { s1[tid] += s1[tid + st]; s2[tid] += s2[tid + st]; }
        __syncthreads();
    }
    double mean = s1[0] / DD;
    float var = (float)(s2[0] / DD - mean * mean);
    float fm = (float)mean;
    float inv = rsqrtf(var + EPSF);
    for (int i = 0; i < 4; ++i) {
        int d = tid + i * 256;
        hn[r * DD + d] = (vals[i] - fm) * inv * g[d] + bb[d];
    }
}

// one block per (b,h): scores -> softmax -> z
__global__ __launch_bounds__(256) void attn_kernel(const float* __restrict__ qkv, float* __restrict__ z) {
    __shared__ float ks[TOK][DHH + 1];
    __shared__ float vs[TOK][DHH + 1];
    __shared__ float ss[TOK][TOK];
    int bh = blockIdx.x;
    int b = bh / HH, h = bh % HH;
    int tid = threadIdx.x;
    for (int i = tid; i < TOK * DHH; i += 256) {
        int l = i / DHH, d = i % DHH;
        long base = (long)(b * TOK + l) * 1536;
        ks[l][d] = qkv[base + 512 + h * DHH + d];
        vs[l][d] = qkv[base + 1024 + h * DHH + d];
    }
    __syncthreads();
    for (int i = tid; i < TOK * TOK; i += 256) {
        int l = i / TOK, m = i % TOK;
        const float* qrow = qkv + (long)(b * TOK + l) * 1536 + h * DHH;
        float acc = 0.f;
        for (int d = 0; d < DHH; ++d) acc += qrow[d] * ks[m][d];
        ss[l][m] = acc * 0.125f;  // DH^-0.5
    }
    __syncthreads();
    if (tid < TOK) {
        float mx = -INFINITY;
        for (int m = 0; m < TOK; ++m) mx = fmaxf(mx, ss[tid][m]);
        float sum = 0.f;
        for (int m = 0; m < TOK; ++m) { float e = expf(ss[tid][m] - mx); ss[tid][m] = e; sum += e; }
        float invs = 1.f / sum;
        for (int m = 0; m < TOK; ++m) ss[tid][m] *= invs;
    }
    __syncthreads();
    for (int i = tid; i < TOK * DHH; i += 256) {
        int l = i / DHH, d = i % DHH;
        float acc = 0.f;
        for (int m = 0; m < TOK; ++m) acc += ss[l][m] * vs[m][d];
        z[(long)(b * TOK + l) * INNER_ + h * DHH + d] = acc;
    }
}

__global__ void final_kernel(const float* __restrict__ t, float* __restrict__ out) {
    int gid = blockIdx.x * blockDim.x + threadIdx.x;
    if (gid >= BB * PP * DD) return;
    int d = gid % DD; int p = (gid / DD) % PP; int b = gid / (DD * PP);
    out[gid] = t[((long)b * TOK + 1 + p) * DD + d];
}

static inline int ceil_div(long a, long b) { return (int)((a + b - 1) / b); }

extern "C" void kernel_launch(void* const* d_in, const int* in_sizes, int n_in,
                              void* d_out, int out_size, void* d_ws, size_t ws_size,
                              hipStream_t stream) {
    const float* x    = (const float*)d_in[0];
    const float* pos  = (const float*)d_in[1];
    const float* w1   = (const float*)d_in[2];
    const float* g1   = (const float*)d_in[3];
    const float* b1   = (const float*)d_in[4];
    const float* w2   = (const float*)d_in[5];
    const float* g2   = (const float*)d_in[6];
    const float* b2   = (const float*)d_in[7];
    const float* w3   = (const float*)d_in[8];
    const float* g3   = (const float*)d_in[9];
    const float* b3   = (const float*)d_in[10];
    const float* w4   = (const float*)d_in[11];
    const float* g4   = (const float*)d_in[12];
    const float* b4   = (const float*)d_in[13];
    const float* w5   = (const float*)d_in[14];
    const float* g5   = (const float*)d_in[15];
    const float* b5   = (const float*)d_in[16];
    const float* cls  = (const float*)d_in[17];
    const float* ln1g = (const float*)d_in[18];
    const float* ln1b = (const float*)d_in[19];
    const float* wqkv = (const float*)d_in[20];
    const float* wout = (const float*)d_in[21];
    const float* bout = (const float*)d_in[22];
    const float* ln2g = (const float*)d_in[23];
    const float* ln2b = (const float*)d_in[24];
    const float* wff1 = (const float*)d_in[25];
    const float* bff1 = (const float*)d_in[26];
    const float* wff2 = (const float*)d_in[27];
    const float* bff2 = (const float*)d_in[28];
    float* out = (float*)d_out;

    // ---- workspace layout ----
    char* ws = (char*)d_ws;
    size_t off = 0;
    auto alloc = [&](size_t bytes) -> char* {
        char* ptr = ws + off;
        off = (off + bytes + 255) & ~(size_t)255;
        return ptr;
    };
    float*  h      = (float*)alloc((size_t)BB * 512 * NN * 4);     // concat features [B,512,N]
    float*  t      = (float*)alloc((size_t)BB * TOK * DD * 4);
    float*  hn     = (float*)alloc((size_t)BB * TOK * DD * 4);
    float*  qkvb   = (float*)alloc((size_t)BB * TOK * 1536 * 4);
    float*  zb     = (float*)alloc((size_t)BB * TOK * INNER_ * 4);
    float*  ub     = (float*)alloc((size_t)BB * TOK * MLPD * 4);
    double* dsum   = (double*)alloc(1024 * 8);
    double* dsq    = (double*)alloc(1024 * 8);
    float*  scaleb = (float*)alloc(1024 * 4);
    float*  shiftb = (float*)alloc(1024 * 4);
    // union region: (pts,xx,idx,p,q) during edge convs, then y5 after conv4
    size_t ubase = off;
    float* y5 = (float*)(ws + ubase);                               // [B,1024,N] = 64 MB
    size_t uoff = ubase;
    auto ualloc = [&](size_t bytes) -> char* {
        char* ptr = ws + uoff;
        uoff = (uoff + bytes + 255) & ~(size_t)255;
        return ptr;
    };
    float* pts  = (float*)ualloc((size_t)BB * 3 * NN * 4);
    float* xx   = (float*)ualloc((size_t)BB * NN * 4);
    int*   idxb = (int*)  ualloc((size_t)BB * NN * KK * 4);
    float* pbuf = (float*)ualloc((size_t)BB * NN * 256 * 4);
    float* qbuf = (float*)ualloc((size_t)BB * NN * 256 * 4);
    size_t need = ubase + (size_t)BB * DD * NN * 4;
    if (ws_size < need) return;  // insufficient scratch: fail loudly rather than corrupt

    // ---- stage 1: transpose points ----
    transpose_x_kernel<<<ceil_div((long)BB * NN * 3, 256), 256, 0, stream>>>(x, pts);

    // ---- stage 2: four EdgeConv blocks ----
    auto run_conv = [&](const float* xin, int xbs, int C, const float* w,
                        const float* g, const float* bb, float* hout, int O) {
        sqnorm_kernel<<<ceil_div((long)BB * NN, 256), 256, 0, stream>>>(xin, xbs, C, xx);
        knn_kernel<<<BB * NN, 256, 0, stream>>>(xin, xbs, C, xx, idxb);
        pq_kernel<<<ceil_div((long)BB * NN * O, 256), 256, 0, stream>>>(xin, xbs, C, w, O, pbuf, qbuf);
        zero_stats_kernel<<<4, 256, 0, stream>>>(dsum, dsq);
        edge_stats_kernel<<<256, 256, 0, stream>>>(pbuf, qbuf, idxb, O, dsum, dsq);
        bn_finalize_kernel<<<1, 256, 0, stream>>>(dsum, dsq, g, bb, O, (double)BB * NN * KK, scaleb, shiftb);
        edge_out_kernel<<<ceil_div((long)BB * NN * O, 256), 256, 0, stream>>>(
            pbuf, qbuf, idxb, O, scaleb, shiftb, hout, 512 * NN);
    };
    run_conv(pts, 3 * NN, 3, w1, g1, b1, h, 64);                            // x1 -> h[:, 0:64]
    run_conv(h, 512 * NN, 64, w2, g2, b2, h + 64 * NN, 64);                 // x2 -> h[:, 64:128]
    run_conv(h + 64 * NN, 512 * NN, 64, w3, g3, b3, h + 128 * NN, 128);     // x3 -> h[:,128:256]
    run_conv(h + 128 * NN, 512 * NN, 128, w4, g4, b4, h + 256 * NN, 256);   // x4 -> h[:,256:512]

    // ---- stage 3: conv5 (y5[b,o,n] = w5·h) + BN + lrelu + patch max-pool ----
    {
        dim3 grid(NN / 64, DD / 64, BB);
        gemm_kernel<<<grid, 256, 0, stream>>>(w5, h, nullptr, y5,
                                              DD, 512, NN, 0L, (long)512 * NN, (long)DD * NN, 0);
    }
    bn5_stats_kernel<<<DD, 256, 0, stream>>>(y5, g5, b5, scaleb, shiftb);
    pool_kernel<<<ceil_div((long)BB * TOK * DD, 256), 256, 0, stream>>>(y5, scaleb, shiftb, cls, t);

    // ---- stage 4: transformer ----
    const int M = BB * TOK;  // 520 rows
    for (int i = 0; i < DEPTH_; ++i) {
        ln_kernel<<<M, 256, 0, stream>>>(t, pos, ln1g + i * DD, ln1b + i * DD, hn, 1);
        {
            dim3 grid(1536 / 64, ceil_div(M, 64), 1);
            gemm_kernel<<<grid, 256, 0, stream>>>(hn, wqkv + (size_t)i * DD * 1536, nullptr, qkvb,
                                                  M, DD, 1536, 0L, 0L, 0L, 0);
        }
        attn_kernel<<<BB * HH, 256, 0, stream>>>(qkvb, zb);
        {
            dim3 grid(DD / 64, ceil_div(M, 64), 1);
            gemm_kernel<<<grid, 256, 0, stream>>>(zb, wout + (size_t)i * INNER_ * DD, bout + i * DD, t,
                                                  M, INNER_, DD, 0L, 0L, 0L, GEMM_ACC);
        }
        ln_kernel<<<M, 256, 0, stream>>>(t, nullptr, ln2g + i * DD, ln2b + i * DD, hn, 0);
        {
            dim3 grid(MLPD / 64, ceil_div(M, 64), 1);
            gemm_kernel<<<grid, 256, 0, stream>>>(hn, wff1 + (size_t)i * DD * MLPD, bff1 + i * MLPD, ub,
                                                  M, DD, MLPD, 0L, 0L, 0L, GEMM_GELU);
        }
        {
            dim3 grid(DD / 64, ceil_div(M, 64), 1);
            gemm_kernel<<<grid, 256, 0, stream>>>(ub, wff2 + (size_t)i * MLPD * DD, bff2 + i * DD, t,
                                                  M, MLPD, DD, 0L, 0L, 0L, GEMM_ACC);
        }
    }

    // ---- stage 5: output t[:,1:] ----
    final_kernel<<<ceil_div((long)BB * PP * DD, 256), 256, 0, stream>>>(t, out);
}

// Round 2
// 6387.210 us; speedup vs baseline: 1.7173x; 1.7173x over previous
//
#include <hip/hip_runtime.h>
#include <math.h>

// ---- problem constants ----
#define BB 8
#define NN 2048
#define PSZ 32
#define PP 64
#define DD 1024
#define MLPD 2048
#define DEPTH_ 6
#define HH 8
#define DHH 64
#define INNER_ 512
#define KK 20
#define TOK 65
#define EPSF 1e-5f

#define GEMM_ACC 1
#define GEMM_GELU 2

// x [B,N,3] -> pts [B,3,N]
__global__ void transpose_x_kernel(const float* __restrict__ x, float* __restrict__ pts) {
    int gid = blockIdx.x * blockDim.x + threadIdx.x;
    if (gid >= BB * NN * 3) return;
    int c = gid % 3; int n = (gid / 3) % NN; int b = gid / (3 * NN);
    pts[(b * 3 + c) * NN + n] = x[gid];
}

// xx[b,n] = sum_c x[b,c,n]^2   (x has per-batch channel stride bs)
__global__ void sqnorm_kernel(const float* __restrict__ x, int bs, int C, float* __restrict__ xx) {
    int gid = blockIdx.x * blockDim.x + threadIdx.x;
    if (gid >= BB * NN) return;
    int n = gid % NN; int b = gid / NN;
    const float* xp = x + b * bs + n;
    float s = 0.f;
    for (int c = 0; c < C; ++c) { float v = xp[c * NN]; s += v * v; }
    xx[gid] = s;
}

// one block per (b,n): dist row in LDS, 20 argmax rounds (ties -> smallest idx)
__global__ __launch_bounds__(256) void knn_kernel(const float* __restrict__ x, int bs, int C,
                                                  const float* __restrict__ xx, int* __restrict__ idx) {
    __shared__ float sdist[NN];
    __shared__ float sc[128];
    __shared__ float rval[256];
    __shared__ int   ridx[256];
    int bn = blockIdx.x;
    int b = bn / NN, n = bn % NN;
    int tid = threadIdx.x;
    for (int c = tid; c < C; c += 256) sc[c] = x[b * bs + c * NN + n];
    __syncthreads();
    float xn = xx[bn];
    for (int mi = 0; mi < NN / 256; ++mi) {
        int m = tid + mi * 256;
        float acc = 0.f;
        const float* xp = x + b * bs + m;
        for (int c = 0; c < C; ++c) acc += sc[c] * xp[c * NN];
        sdist[m] = 2.f * acc - xn - xx[b * NN + m];
    }
    __syncthreads();
    for (int kk = 0; kk < KK; ++kk) {
        float bv = -INFINITY; int bi = NN;
        for (int mi = 0; mi < NN / 256; ++mi) {
            int m = tid + mi * 256;
            float v = sdist[m];
            if (v > bv) { bv = v; bi = m; }   // within-thread m increases -> keeps smallest idx on tie
        }
        rval[tid] = bv; ridx[tid] = bi;
        __syncthreads();
        for (int s = 128; s > 0; s >>= 1) {
            if (tid < s) {
                float ov = rval[tid + s]; int oi = ridx[tid + s];
                if (ov > rval[tid] || (ov == rval[tid] && oi < ridx[tid])) { rval[tid] = ov; ridx[tid] = oi; }
            }
            __syncthreads();
        }
        if (tid == 0) { idx[bn * KK + kk] = ridx[0]; sdist[ridx[0]] = -INFINITY; }
        __syncthreads();
    }
}

// p[b,n,o] = sum_c x[b,c,n]*w[o,c]; q[b,n,o] = sum_c x[b,c,n]*(w[o,C+c]-w[o,c])
// LDS-staged tile version: 32 o's x 32 n's per block; weights staged transposed
// (coalesced global reads, padded rows to avoid bank conflicts); x tile staged coalesced.
__global__ __launch_bounds__(256) void pq_kernel(const float* __restrict__ x, int bs, int C,
                                                 const float* __restrict__ w, int O,
                                                 float* __restrict__ p, float* __restrict__ q) {
    __shared__ float wT[256][33];   // [c2][o], c2 < 2C <= 256, o < 32; +1 pad
    __shared__ float xs[128][32];   // [c][n_local], c < C <= 128
    int b = blockIdx.z;
    int o0 = blockIdx.y * 32;
    int n0 = blockIdx.x * 32;
    int tid = threadIdx.x;
    // stage weights: lanes run over c2 (contiguous in w) -> coalesced
    for (int i = tid; i < 2 * C * 32; i += 256) {
        int c2 = i % (2 * C), o = i / (2 * C);
        wT[c2][o] = w[(o0 + o) * 2 * C + c2];
    }
    // stage x tile: lanes run over n (contiguous in x) -> coalesced
    for (int i = tid; i < C * 32; i += 256) {
        int nl = i % 32, c = i / 32;
        xs[c][nl] = x[b * bs + c * NN + n0 + nl];
    }
    __syncthreads();
    int o_l = tid & 31;
    int n_base = (tid >> 5) * 4;    // 8 groups x 4 points
    float ps[4] = {0.f, 0.f, 0.f, 0.f};
    float qs[4] = {0.f, 0.f, 0.f, 0.f};
    for (int c = 0; c < C; ++c) {
        float4 xv = *(const float4*)&xs[c][n_base];
        float wa = wT[c][o_l];
        float wb = wT[C + c][o_l];
        float d = wb - wa;
        ps[0] += xv.x * wa; qs[0] += xv.x * d;
        ps[1] += xv.y * wa; qs[1] += xv.y * d;
        ps[2] += xv.z * wa; qs[2] += xv.z * d;
        ps[3] += xv.w * wa; qs[3] += xv.w * d;
    }
    for (int j = 0; j < 4; ++j) {
        long r = (long)(b * NN + n0 + n_base + j) * O + o0 + o_l;
        p[r] = ps[j];
        q[r] = qs[j];
    }
}

__global__ void zero_stats_kernel(double* __restrict__ s1, double* __restrict__ s2) {
    int t = blockIdx.x * blockDim.x + threadIdx.x;
    if (t < 1024) { s1[t] = 0.0; s2[t] = 0.0; }
}

// BN stats over (b,n,k) per output channel, y = p[b,j,o] + q[b,n,o]
__global__ __launch_bounds__(256) void edge_stats_kernel(const float* __restrict__ p, const float* __restrict__ q,
                                                         const int* __restrict__ idx, int O,
                                                         double* __restrict__ gsum, double* __restrict__ gsumsq) {
    int tid = threadIdx.x;
    int o = tid % O;
    int grp = tid / O;
    int ngrp = 256 / O;
    int rows_per_blk = (BB * NN) / gridDim.x;
    int r0 = blockIdx.x * rows_per_blk;
    double s = 0.0, ss = 0.0;
    for (int r = r0 + grp; r < r0 + rows_per_blk; r += ngrp) {
        int b = r / NN;
        float qv = q[r * O + o];
        for (int k = 0; k < KK; ++k) {
            int j = idx[r * KK + k];
            float v = p[(b * NN + j) * O + o] + qv;
            s += v; ss += (double)v * v;
        }
    }
    atomicAdd(&gsum[o], s);
    atomicAdd(&gsumsq[o], ss);
}

__global__ void bn_finalize_kernel(const double* __restrict__ gsum, const double* __restrict__ gsumsq,
                                   const float* __restrict__ g, const float* __restrict__ bb, int O, double cnt,
                                   float* __restrict__ scale, float* __restrict__ shift) {
    int o = blockIdx.x * blockDim.x + threadIdx.x;
    if (o >= O) return;
    double mean = gsum[o] / cnt;
    double var = gsumsq[o] / cnt - mean * mean;
    float inv = rsqrtf((float)var + EPSF);
    float sc = g[o] * inv;
    scale[o] = sc;
    shift[o] = bb[o] - (float)mean * sc;
}

// out[b,o,n] = max_k lrelu((p[b,j,o]+q[b,n,o])*scale+shift); out has per-batch channel stride obs
__global__ void edge_out_kernel(const float* __restrict__ p, const float* __restrict__ q,
                                const int* __restrict__ idx, int O,
                                const float* __restrict__ scale, const float* __restrict__ shift,
                                float* __restrict__ out, int obs) {
    int gid = blockIdx.x * blockDim.x + threadIdx.x;
    if (gid >= BB * NN * O) return;
    int o = gid % O; int n = (gid / O) % NN; int b = gid / (O * NN);
    int r = b * NN + n;
    float qv = q[r * O + o];
    float sc = scale[o], sh = shift[o];
    float m = -INFINITY;
    for (int k = 0; k < KK; ++k) {
        int j = idx[r * KK + k];
        float v = (p[(b * NN + j) * O + o] + qv) * sc + sh;
        v = (v >= 0.f) ? v : 0.2f * v;
        m = fmaxf(m, v);
    }
    out[b * obs + o * NN + n] = m;
}

// generic fp32 GEMM: out[M,N] = A[M,K]·B[K,N] (+bias per col, optional GELU, optional accumulate)
// 64x64 block tile, 16 k-step, 4x4 per thread. K must be a multiple of 16 (true for all call sites).
__global__ __launch_bounds__(256) void gemm_kernel(const float* __restrict__ A, const float* __restrict__ Bm,
                                                   const float* __restrict__ bias, float* __restrict__ out,
                                                   int M, int Kd, int Nd, long sA, long sB, long sO, int flags) {
    __shared__ float As[16][65];
    __shared__ float Bs[16][64];
    const float* Ab = A + (long)blockIdx.z * sA;
    const float* Bb = Bm + (long)blockIdx.z * sB;
    float* Ob = out + (long)blockIdx.z * sO;
    int row0 = blockIdx.y * 64, col0 = blockIdx.x * 64;
    int tid = threadIdx.x;
    int ty = tid / 16, tx = tid % 16;
    float acc[4][4] = {};
    for (int k0 = 0; k0 < Kd; k0 += 16) {
        for (int i = 0; i < 4; ++i) {
            int li = tid + i * 256;
            int m = li / 16, kk = li % 16;
            int r = row0 + m;
            As[kk][m] = (r < M) ? Ab[(long)r * Kd + k0 + kk] : 0.f;
        }
        for (int i = 0; i < 4; ++i) {
            int li = tid + i * 256;
            int kk = li / 64, n = li % 64;
            int c = col0 + n;
            Bs[kk][n] = (c < Nd) ? Bb[(long)(k0 + kk) * Nd + c] : 0.f;
        }
        __syncthreads();
        for (int kk = 0; kk < 16; ++kk) {
            float a[4], bv[4];
            for (int i = 0; i < 4; ++i) a[i] = As[kk][ty * 4 + i];
            for (int j = 0; j < 4; ++j) bv[j] = Bs[kk][tx * 4 + j];
            for (int i = 0; i < 4; ++i)
                for (int j = 0; j < 4; ++j)
                    acc[i][j] += a[i] * bv[j];
        }
        __syncthreads();
    }
    for (int i = 0; i < 4; ++i) {
        int r = row0 + ty * 4 + i;
        if (r >= M) continue;
        for (int j = 0; j < 4; ++j) {
            int c = col0 + tx * 4 + j;
            if (c >= Nd) continue;
            float v = acc[i][j];
            if (bias) v += bias[c];
            if (flags & GEMM_GELU) v = 0.5f * v * (1.f + erff(v * 0.70710678118654752f));
            long oidx = (long)r * Nd + c;
            if (flags & GEMM_ACC) Ob[oidx] += v; else Ob[oidx] = v;
        }
    }
}

// BN5 stats: per channel d over (b,n) of y5[b,d,n]; writes scale/shift directly
__global__ __launch_bounds__(256) void bn5_stats_kernel(const float* __restrict__ y5, const float* __restrict__ g,
                                                        const float* __restrict__ bb,
                                                        float* __restrict__ scale, float* __restrict__ shift) {
    __shared__ double ssum[256], ssq[256];
    int d = blockIdx.x;
    int tid = threadIdx.x;
    double s = 0.0, sq = 0.0;
    for (int b = 0; b < BB; ++b) {
        const float* row = y5 + ((long)b * DD + d) * NN;
        for (int n = tid; n < NN; n += 256) { float v = row[n]; s += v; sq += (double)v * v; }
    }
    ssum[tid] = s; ssq[tid] = sq;
    __syncthreads();
    for (int st = 128; st > 0; st >>= 1) {
        if (tid < st) { ssum[tid] += ssum[tid + st]; ssq[tid] += ssq[tid + st]; }
        __syncthreads();
    }
    if (tid == 0) {
        double cnt = (double)BB * NN;
        double mean = ssum[0] / cnt;
        double var = ssq[0] / cnt - mean * mean;
        float inv = rsqrtf((float)var + EPSF);
        float sc = g[d] * inv;
        scale[d] = sc;
        shift[d] = bb[d] - (float)mean * sc;
    }
}

// tokens: t[b,0,:]=cls; t[b,1+p,d] = max over 32 pts of lrelu(y5*scale+shift)
__global__ void pool_kernel(const float* __restrict__ y5, const float* __restrict__ scale,
                            const float* __restrict__ shift, const float* __restrict__ cls,
                            float* __restrict__ t) {
    int gid = blockIdx.x * blockDim.x + threadIdx.x;
    if (gid >= BB * TOK * DD) return;
    int d = gid % DD; int l = (gid / DD) % TOK; int b = gid / (DD * TOK);
    float v;
    if (l == 0) {
        v = cls[d];
    } else {
        int pp = l - 1;
        const float* row = y5 + ((long)b * DD + d) * NN + pp * PSZ;
        float sc = scale[d], sh = shift[d];
        float m = -INFINITY;
        for (int i = 0; i < PSZ; ++i) {
            float u = row[i] * sc + sh;
            u = (u >= 0.f) ? u : 0.2f * u;
            m = fmaxf(m, u);
        }
        v = m;
    }
    t[gid] = v;
}

// per-token LayerNorm; if addpos: t += pos first (written back), then normalize
__global__ __launch_bounds__(256) void ln_kernel(float* __restrict__ t, const float* __restrict__ pos,
                                                 const float* __restrict__ g, const float* __restrict__ bb,
                                                 float* __restrict__ hn, int addpos) {
    __shared__ double s1[256], s2[256];
    long r = blockIdx.x;
    int tid = threadIdx.x;
    float vals[4];
    double s = 0.0, sq = 0.0;
    for (int i = 0; i < 4; ++i) {
        int d = tid + i * 256;
        float v = t[r * DD + d];
        if (addpos) { v += pos[r * DD + d]; t[r * DD + d] = v; }
        vals[i] = v; s += v; sq += (double)v * v;
    }
    s1[tid] = s; s2[tid] = sq;
    __syncthreads();
    for (int st = 128; st > 0; st >>= 1) {
        if (tid < st) { s1[tid] += s1[tid + st]; s2[tid] += s2[tid + st]; }
        __syncthreads();
    }
    double mean = s1[0] / DD;
    float var = (float)(s2[0] / DD - mean * mean);
    float fm = (float)mean;
    float inv = rsqrtf(var + EPSF);
    for (int i = 0; i < 4; ++i) {
        int d = tid + i * 256;
        hn[r * DD + d] = (vals[i] - fm) * inv * g[d] + bb[d];
    }
}

// one block per (b,h): scores -> softmax -> z
__global__ __launch_bounds__(256) void attn_kernel(const float* __restrict__ qkv, float* __restrict__ z) {
    __shared__ float ks[TOK][DHH + 1];
    __shared__ float vs[TOK][DHH + 1];
    __shared__ float ss[TOK][TOK];
    int bh = blockIdx.x;
    int b = bh / HH, h = bh % HH;
    int tid = threadIdx.x;
    for (int i = tid; i < TOK * DHH; i += 256) {
        int l = i / DHH, d = i % DHH;
        long base = (long)(b * TOK + l) * 1536;
        ks[l][d] = qkv[base + 512 + h * DHH + d];
        vs[l][d] = qkv[base + 1024 + h * DHH + d];
    }
    __syncthreads();
    for (int i = tid; i < TOK * TOK; i += 256) {
        int l = i / TOK, m = i % TOK;
        const float* qrow = qkv + (long)(b * TOK + l) * 1536 + h * DHH;
        float acc = 0.f;
        for (int d = 0; d < DHH; ++d) acc += qrow[d] * ks[m][d];
        ss[l][m] = acc * 0.125f;  // DH^-0.5
    }
    __syncthreads();
    if (tid < TOK) {
        float mx = -INFINITY;
        for (int m = 0; m < TOK; ++m) mx = fmaxf(mx, ss[tid][m]);
        float sum = 0.f;
        for (int m = 0; m < TOK; ++m) { float e = expf(ss[tid][m] - mx); ss[tid][m] = e; sum += e; }
        float invs = 1.f / sum;
        for (int m = 0; m < TOK; ++m) ss[tid][m] *= invs;
    }
    __syncthreads();
    for (int i = tid; i < TOK * DHH; i += 256) {
        int l = i / DHH, d = i % DHH;
        float acc = 0.f;
        for (int m = 0; m < TOK; ++m) acc += ss[l][m] * vs[m][d];
        z[(long)(b * TOK + l) * INNER_ + h * DHH + d] = acc;
    }
}

__global__ void final_kernel(const float* __restrict__ t, float* __restrict__ out) {
    int gid = blockIdx.x * blockDim.x + threadIdx.x;
    if (gid >= BB * PP * DD) return;
    int d = gid % DD; int p = (gid / DD) % PP; int b = gid / (DD * PP);
    out[gid] = t[((long)b * TOK + 1 + p) * DD + d];
}

static inline int ceil_div(long a, long b) { return (int)((a + b - 1) / b); }

extern "C" void kernel_launch(void* const* d_in, const int* in_sizes, int n_in,
                              void* d_out, int out_size, void* d_ws, size_t ws_size,
                              hipStream_t stream) {
    const float* x    = (const float*)d_in[0];
    const float* pos  = (const float*)d_in[1];
    const float* w1   = (const float*)d_in[2];
    const float* g1   = (const float*)d_in[3];
    const float* b1   = (const float*)d_in[4];
    const float* w2   = (const float*)d_in[5];
    const float* g2   = (const float*)d_in[6];
    const float* b2   = (const float*)d_in[7];
    const float* w3   = (const float*)d_in[8];
    const float* g3   = (const float*)d_in[9];
    const float* b3   = (const float*)d_in[10];
    const float* w4   = (const float*)d_in[11];
    const float* g4   = (const float*)d_in[12];
    const float* b4   = (const float*)d_in[13];
    const float* w5   = (const float*)d_in[14];
    const float* g5   = (const float*)d_in[15];
    const float* b5   = (const float*)d_in[16];
    const float* cls  = (const float*)d_in[17];
    const float* ln1g = (const float*)d_in[18];
    const float* ln1b = (const float*)d_in[19];
    const float* wqkv = (const float*)d_in[20];
    const float* wout = (const float*)d_in[21];
    const float* bout = (const float*)d_in[22];
    const float* ln2g = (const float*)d_in[23];
    const float* ln2b = (const float*)d_in[24];
    const float* wff1 = (const float*)d_in[25];
    const float* bff1 = (const float*)d_in[26];
    const float* wff2 = (const float*)d_in[27];
    const float* bff2 = (const float*)d_in[28];
    float* out = (float*)d_out;

    // ---- workspace layout ----
    char* ws = (char*)d_ws;
    size_t off = 0;
    auto alloc = [&](size_t bytes) -> char* {
        char* ptr = ws + off;
        off = (off + bytes + 255) & ~(size_t)255;
        return ptr;
    };
    float*  h      = (float*)alloc((size_t)BB * 512 * NN * 4);     // concat features [B,512,N]
    float*  t      = (float*)alloc((size_t)BB * TOK * DD * 4);
    float*  hn     = (float*)alloc((size_t)BB * TOK * DD * 4);
    float*  qkvb   = (float*)alloc((size_t)BB * TOK * 1536 * 4);
    float*  zb     = (float*)alloc((size_t)BB * TOK * INNER_ * 4);
    float*  ub     = (float*)alloc((size_t)BB * TOK * MLPD * 4);
    double* dsum   = (double*)alloc(1024 * 8);
    double* dsq    = (double*)alloc(1024 * 8);
    float*  scaleb = (float*)alloc(1024 * 4);
    float*  shiftb = (float*)alloc(1024 * 4);
    // union region: (pts,xx,idx,p,q) during edge convs, then y5 after conv4
    size_t ubase = off;
    float* y5 = (float*)(ws + ubase);                               // [B,1024,N] = 64 MB
    size_t uoff = ubase;
    auto ualloc = [&](size_t bytes) -> char* {
        char* ptr = ws + uoff;
        uoff = (uoff + bytes + 255) & ~(size_t)255;
        return ptr;
    };
    float* pts  = (float*)ualloc((size_t)BB * 3 * NN * 4);
    float* xx   = (float*)ualloc((size_t)BB * NN * 4);
    int*   idxb = (int*)  ualloc((size_t)BB * NN * KK * 4);
    float* pbuf = (float*)ualloc((size_t)BB * NN * 256 * 4);
    float* qbuf = (float*)ualloc((size_t)BB * NN * 256 * 4);
    size_t need = ubase + (size_t)BB * DD * NN * 4;
    if (ws_size < need) return;  // insufficient scratch: fail loudly rather than corrupt

    // ---- stage 1: transpose points ----
    transpose_x_kernel<<<ceil_div((long)BB * NN * 3, 256), 256, 0, stream>>>(x, pts);

    // ---- stage 2: four EdgeConv blocks ----
    auto run_conv = [&](const float* xin, int xbs, int C, const float* w,
                        const float* g, const float* bb, float* hout, int O) {
        sqnorm_kernel<<<ceil_div((long)BB * NN, 256), 256, 0, stream>>>(xin, xbs, C, xx);
        knn_kernel<<<BB * NN, 256, 0, stream>>>(xin, xbs, C, xx, idxb);
        {
            dim3 grid(NN / 32, O / 32, BB);
            pq_kernel<<<grid, 256, 0, stream>>>(xin, xbs, C, w, O, pbuf, qbuf);
        }
        zero_stats_kernel<<<4, 256, 0, stream>>>(dsum, dsq);
        edge_stats_kernel<<<256, 256, 0, stream>>>(pbuf, qbuf, idxb, O, dsum, dsq);
        bn_finalize_kernel<<<1, 256, 0, stream>>>(dsum, dsq, g, bb, O, (double)BB * NN * KK, scaleb, shiftb);
        edge_out_kernel<<<ceil_div((long)BB * NN * O, 256), 256, 0, stream>>>(
            pbuf, qbuf, idxb, O, scaleb, shiftb, hout, 512 * NN);
    };
    run_conv(pts, 3 * NN, 3, w1, g1, b1, h, 64);                            // x1 -> h[:, 0:64]
    run_conv(h, 512 * NN, 64, w2, g2, b2, h + 64 * NN, 64);                 // x2 -> h[:, 64:128]
    run_conv(h + 64 * NN, 512 * NN, 64, w3, g3, b3, h + 128 * NN, 128);     // x3 -> h[:,128:256]
    run_conv(h + 128 * NN, 512 * NN, 128, w4, g4, b4, h + 256 * NN, 256);   // x4 -> h[:,256:512]

    // ---- stage 3: conv5 (y5[b,o,n] = w5·h) + BN + lrelu + patch max-pool ----
    {
        dim3 grid(NN / 64, DD / 64, BB);
        gemm_kernel<<<grid, 256, 0, stream>>>(w5, h, nullptr, y5,
                                              DD, 512, NN, 0L, (long)512 * NN, (long)DD * NN, 0);
    }
    bn5_stats_kernel<<<DD, 256, 0, stream>>>(y5, g5, b5, scaleb, shiftb);
    pool_kernel<<<ceil_div((long)BB * TOK * DD, 256), 256, 0, stream>>>(y5, scaleb, shiftb, cls, t);

    // ---- stage 4: transformer ----
    const int M = BB * TOK;  // 520 rows
    for (int i = 0; i < DEPTH_; ++i) {
        ln_kernel<<<M, 256, 0, stream>>>(t, pos, ln1g + i * DD, ln1b + i * DD, hn, 1);
        {
            dim3 grid(1536 / 64, ceil_div(M, 64), 1);
            gemm_kernel<<<grid, 256, 0, stream>>>(hn, wqkv + (size_t)i * DD * 1536, nullptr, qkvb,
                                                  M, DD, 1536, 0L, 0L, 0L, 0);
        }
        attn_kernel<<<BB * HH, 256, 0, stream>>>(qkvb, zb);
        {
            dim3 grid(DD / 64, ceil_div(M, 64), 1);
            gemm_kernel<<<grid, 256, 0, stream>>>(zb, wout + (size_t)i * INNER_ * DD, bout + i * DD, t,
                                                  M, INNER_, DD, 0L, 0L, 0L, GEMM_ACC);
        }
        ln_kernel<<<M, 256, 0, stream>>>(t, nullptr, ln2g + i * DD, ln2b + i * DD, hn, 0);
        {
            dim3 grid(MLPD / 64, ceil_div(M, 64), 1);
            gemm_kernel<<<grid, 256, 0, stream>>>(hn, wff1 + (size_t)i * DD * MLPD, bff1 + i * MLPD, ub,
                                                  M, DD, MLPD, 0L, 0L, 0L, GEMM_GELU);
        }
        {
            dim3 grid(DD / 64, ceil_div(M, 64), 1);
            gemm_kernel<<<grid, 256, 0, stream>>>(ub, wff2 + (size_t)i * MLPD * DD, bff2 + i * DD, t,
                                                  M, MLPD, DD, 0L, 0L, 0L, GEMM_ACC);
        }
    }

    // ---- stage 5: output t[:,1:] ----
    final_kernel<<<ceil_div((long)BB * PP * DD, 256), 256, 0, stream>>>(t, out);
}

// Round 3
// 5275.152 us; speedup vs baseline: 2.0794x; 1.2108x over previous
//
#include <hip/hip_runtime.h>
#include <math.h>

// ---- problem constants ----
#define BB 8
#define NN 2048
#define PSZ 32
#define PP 64
#define DD 1024
#define MLPD 2048
#define DEPTH_ 6
#define HH 8
#define DHH 64
#define INNER_ 512
#define KK 20
#define TOK 65
#define EPSF 1e-5f

#define GEMM_ACC 1
#define GEMM_GELU 2

// x [B,N,3] -> pts [B,3,N]
__global__ void transpose_x_kernel(const float* __restrict__ x, float* __restrict__ pts) {
    int gid = blockIdx.x * blockDim.x + threadIdx.x;
    if (gid >= BB * NN * 3) return;
    int c = gid % 3; int n = (gid / 3) % NN; int b = gid / (3 * NN);
    pts[(b * 3 + c) * NN + n] = x[gid];
}

// xx[b,n] = sum_c x[b,c,n]^2   (x has per-batch channel stride bs)
__global__ void sqnorm_kernel(const float* __restrict__ x, int bs, int C, float* __restrict__ xx) {
    int gid = blockIdx.x * blockDim.x + threadIdx.x;
    if (gid >= BB * NN) return;
    int n = gid % NN; int b = gid / NN;
    const float* xp = x + b * bs + n;
    float s = 0.f;
    for (int c = 0; c < C; ++c) { float v = xp[c * NN]; s += v * v; }
    xx[gid] = s;
}

// dist[n,m] = 2*sum_c x[c,n]x[c,m] - xx[n] - xx[m], tiled 64x64, per-batch slab in z
__global__ __launch_bounds__(256) void dist_kernel(const float* __restrict__ x, int bs, int C,
                                                   const float* __restrict__ xx, int b0,
                                                   float* __restrict__ dist) {
    __shared__ float As[16][72];
    __shared__ float Bs[16][72];
    int b = b0 + blockIdx.z;
    int n0 = blockIdx.y * 64, m0 = blockIdx.x * 64;
    int tid = threadIdx.x;
    int ty = tid / 16, tx = tid % 16;
    float acc[4][4] = {};
    const float* xb = x + (long)b * bs;
    for (int k0 = 0; k0 < C; k0 += 16) {
        for (int ppp = 0; ppp < 4; ++ppp) {
            int li = tid + ppp * 256;
            int i = li % 64, kk = li / 64;
            int c = k0 + kk;
            As[kk][i] = (c < C) ? xb[c * NN + n0 + i] : 0.f;
            Bs[kk][i] = (c < C) ? xb[c * NN + m0 + i] : 0.f;
        }
        __syncthreads();
        for (int kk = 0; kk < 16; ++kk) {
            float a[4], bv[4];
            *(float4*)a = *(const float4*)&As[kk][ty * 4];
            *(float4*)bv = *(const float4*)&Bs[kk][tx * 4];
            for (int i2 = 0; i2 < 4; ++i2)
                for (int j = 0; j < 4; ++j)
                    acc[i2][j] += a[i2] * bv[j];
        }
        __syncthreads();
    }
    float* db = dist + (long)blockIdx.z * NN * NN;
    for (int i2 = 0; i2 < 4; ++i2) {
        int n = n0 + ty * 4 + i2;
        float xn = xx[b * NN + n];
        float4 st;
        int m = m0 + tx * 4;
        st.x = 2.f * acc[i2][0] - xn - xx[b * NN + m + 0];
        st.y = 2.f * acc[i2][1] - xn - xx[b * NN + m + 1];
        st.z = 2.f * acc[i2][2] - xn - xx[b * NN + m + 2];
        st.w = 2.f * acc[i2][3] - xn - xx[b * NN + m + 3];
        *(float4*)&db[(long)n * NN + m] = st;
    }
}

// one WAVE per row: 32 vals/lane in registers, 20 butterfly-argmax rounds, no barriers.
// tie-break matches lax.top_k: larger value, then smaller index.
__global__ __launch_bounds__(256) void topk_kernel(const float* __restrict__ dist, int b0,
                                                   int* __restrict__ idx) {
    int b = b0 + blockIdx.y;
    int wid = threadIdx.x >> 6, lane = threadIdx.x & 63;
    int n = blockIdx.x * 4 + wid;
    const float* row = dist + ((long)blockIdx.y * NN + n) * NN;
    float vals[32];
    #pragma unroll
    for (int s = 0; s < 32; ++s) vals[s] = row[s * 64 + lane];
    int* op = idx + ((long)b * NN + n) * KK;
    for (int kk = 0; kk < KK; ++kk) {
        float bv = vals[0]; int bsl = 0;
        #pragma unroll
        for (int s = 1; s < 32; ++s) if (vals[s] > bv) { bv = vals[s]; bsl = s; }  // keeps smallest m locally
        int bm = bsl * 64 + lane;
        for (int off = 32; off; off >>= 1) {
            float ov = __shfl_xor(bv, off);
            int om = __shfl_xor(bm, off);
            if (ov > bv || (ov == bv && om < bm)) { bv = ov; bm = om; }
        }
        int wslot = bm >> 6, wlane = bm & 63;
        #pragma unroll
        for (int s = 0; s < 32; ++s)
            if (s == wslot) vals[s] = (lane == wlane) ? -INFINITY : vals[s];  // wslot is wave-uniform
        if (lane == 0) op[kk] = bm;
    }
}

// p[b,n,o] = sum_c x[b,c,n]*w[o,c]; q[b,n,o] = sum_c x[b,c,n]*(w[o,C+c]-w[o,c])
__global__ __launch_bounds__(256) void pq_kernel(const float* __restrict__ x, int bs, int C,
                                                 const float* __restrict__ w, int O,
                                                 float* __restrict__ p, float* __restrict__ q) {
    __shared__ float wT[256][33];   // [c2][o], c2 < 2C <= 256, o < 32; +1 pad
    __shared__ float xs[128][32];   // [c][n_local], c < C <= 128
    int b = blockIdx.z;
    int o0 = blockIdx.y * 32;
    int n0 = blockIdx.x * 32;
    int tid = threadIdx.x;
    for (int i = tid; i < 2 * C * 32; i += 256) {
        int c2 = i % (2 * C), o = i / (2 * C);
        wT[c2][o] = w[(o0 + o) * 2 * C + c2];
    }
    for (int i = tid; i < C * 32; i += 256) {
        int nl = i % 32, c = i / 32;
        xs[c][nl] = x[b * bs + c * NN + n0 + nl];
    }
    __syncthreads();
    int o_l = tid & 31;
    int n_base = (tid >> 5) * 4;
    float ps[4] = {0.f, 0.f, 0.f, 0.f};
    float qs[4] = {0.f, 0.f, 0.f, 0.f};
    for (int c = 0; c < C; ++c) {
        float4 xv = *(const float4*)&xs[c][n_base];
        float wa = wT[c][o_l];
        float wb = wT[C + c][o_l];
        float d = wb - wa;
        ps[0] += xv.x * wa; qs[0] += xv.x * d;
        ps[1] += xv.y * wa; qs[1] += xv.y * d;
        ps[2] += xv.z * wa; qs[2] += xv.z * d;
        ps[3] += xv.w * wa; qs[3] += xv.w * d;
    }
    for (int j = 0; j < 4; ++j) {
        long r = (long)(b * NN + n0 + n_base + j) * O + o0 + o_l;
        p[r] = ps[j];
        q[r] = qs[j];
    }
}

__global__ void zero_stats_kernel(double* __restrict__ s1, double* __restrict__ s2) {
    int t = blockIdx.x * blockDim.x + threadIdx.x;
    if (t < 1024) { s1[t] = 0.0; s2[t] = 0.0; }
}

// BN stats over (b,n,k) per output channel, y = p[b,j,o] + q[b,n,o]
__global__ __launch_bounds__(256) void edge_stats_kernel(const float* __restrict__ p, const float* __restrict__ q,
                                                         const int* __restrict__ idx, int O,
                                                         double* __restrict__ gsum, double* __restrict__ gsumsq) {
    int tid = threadIdx.x;
    int o = tid % O;
    int grp = tid / O;
    int ngrp = 256 / O;
    int rows_per_blk = (BB * NN) / gridDim.x;
    int r0 = blockIdx.x * rows_per_blk;
    double s = 0.0, ss = 0.0;
    for (int r = r0 + grp; r < r0 + rows_per_blk; r += ngrp) {
        int b = r / NN;
        float qv = q[r * O + o];
        for (int k = 0; k < KK; ++k) {
            int j = idx[r * KK + k];
            float v = p[(b * NN + j) * O + o] + qv;
            s += v; ss += (double)v * v;
        }
    }
    atomicAdd(&gsum[o], s);
    atomicAdd(&gsumsq[o], ss);
}

__global__ void bn_finalize_kernel(const double* __restrict__ gsum, const double* __restrict__ gsumsq,
                                   const float* __restrict__ g, const float* __restrict__ bb, int O, double cnt,
                                   float* __restrict__ scale, float* __restrict__ shift) {
    int o = blockIdx.x * blockDim.x + threadIdx.x;
    if (o >= O) return;
    double mean = gsum[o] / cnt;
    double var = gsumsq[o] / cnt - mean * mean;
    float inv = rsqrtf((float)var + EPSF);
    float sc = g[o] * inv;
    scale[o] = sc;
    shift[o] = bb[o] - (float)mean * sc;
}

// out[b,o,n] = max_k lrelu((p[b,j,o]+q[b,n,o])*scale+shift); out has per-batch channel stride obs
__global__ void edge_out_kernel(const float* __restrict__ p, const float* __restrict__ q,
                                const int* __restrict__ idx, int O,
                                const float* __restrict__ scale, const float* __restrict__ shift,
                                float* __restrict__ out, int obs) {
    int gid = blockIdx.x * blockDim.x + threadIdx.x;
    if (gid >= BB * NN * O) return;
    int o = gid % O; int n = (gid / O) % NN; int b = gid / (O * NN);
    int r = b * NN + n;
    float qv = q[r * O + o];
    float sc = scale[o], sh = shift[o];
    float m = -INFINITY;
    for (int k = 0; k < KK; ++k) {
        int j = idx[r * KK + k];
        float v = (p[(b * NN + j) * O + o] + qv) * sc + sh;
        v = (v >= 0.f) ? v : 0.2f * v;
        m = fmaxf(m, v);
    }
    out[b * obs + o * NN + n] = m;
}

// generic fp32 GEMM: out[M,N] = A[M,K]·B[K,N] (+bias per col, optional GELU, optional accumulate)
__global__ __launch_bounds__(256) void gemm_kernel(const float* __restrict__ A, const float* __restrict__ Bm,
                                                   const float* __restrict__ bias, float* __restrict__ out,
                                                   int M, int Kd, int Nd, long sA, long sB, long sO, int flags) {
    __shared__ float As[16][65];
    __shared__ float Bs[16][64];
    const float* Ab = A + (long)blockIdx.z * sA;
    const float* Bb = Bm + (long)blockIdx.z * sB;
    float* Ob = out + (long)blockIdx.z * sO;
    int row0 = blockIdx.y * 64, col0 = blockIdx.x * 64;
    int tid = threadIdx.x;
    int ty = tid / 16, tx = tid % 16;
    float acc[4][4] = {};
    for (int k0 = 0; k0 < Kd; k0 += 16) {
        for (int i = 0; i < 4; ++i) {
            int li = tid + i * 256;
            int m = li / 16, kk = li % 16;
            int r = row0 + m;
            As[kk][m] = (r < M) ? Ab[(long)r * Kd + k0 + kk] : 0.f;
        }
        for (int i = 0; i < 4; ++i) {
            int li = tid + i * 256;
            int kk = li / 64, n = li % 64;
            int c = col0 + n;
            Bs[kk][n] = (c < Nd) ? Bb[(long)(k0 + kk) * Nd + c] : 0.f;
        }
        __syncthreads();
        for (int kk = 0; kk < 16; ++kk) {
            float a[4], bv[4];
            for (int i = 0; i < 4; ++i) a[i] = As[kk][ty * 4 + i];
            for (int j = 0; j < 4; ++j) bv[j] = Bs[kk][tx * 4 + j];
            for (int i = 0; i < 4; ++i)
                for (int j = 0; j < 4; ++j)
                    acc[i][j] += a[i] * bv[j];
        }
        __syncthreads();
    }
    for (int i = 0; i < 4; ++i) {
        int r = row0 + ty * 4 + i;
        if (r >= M) continue;
        for (int j = 0; j < 4; ++j) {
            int c = col0 + tx * 4 + j;
            if (c >= Nd) continue;
            float v = acc[i][j];
            if (bias) v += bias[c];
            if (flags & GEMM_GELU) v = 0.5f * v * (1.f + erff(v * 0.70710678118654752f));
            long oidx = (long)r * Nd + c;
            if (flags & GEMM_ACC) Ob[oidx] += v; else Ob[oidx] = v;
        }
    }
}

// BN5 stats: per channel d over (b,n) of y5[b,d,n]; writes scale/shift directly
__global__ __launch_bounds__(256) void bn5_stats_kernel(const float* __restrict__ y5, const float* __restrict__ g,
                                                        const float* __restrict__ bb,
                                                        float* __restrict__ scale, float* __restrict__ shift) {
    __shared__ double ssum[256], ssq[256];
    int d = blockIdx.x;
    int tid = threadIdx.x;
    double s = 0.0, sq = 0.0;
    for (int b = 0; b < BB; ++b) {
        const float* row = y5 + ((long)b * DD + d) * NN;
        for (int n = tid; n < NN; n += 256) { float v = row[n]; s += v; sq += (double)v * v; }
    }
    ssum[tid] = s; ssq[tid] = sq;
    __syncthreads();
    for (int st = 128; st > 0; st >>= 1) {
        if (tid < st) { ssum[tid] += ssum[tid + st]; ssq[tid] += ssq[tid + st]; }
        __syncthreads();
    }
    if (tid == 0) {
        double cnt = (double)BB * NN;
        double mean = ssum[0] / cnt;
        double var = ssq[0] / cnt - mean * mean;
        float inv = rsqrtf((float)var + EPSF);
        float sc = g[d] * inv;
        scale[d] = sc;
        shift[d] = bb[d] - (float)mean * sc;
    }
}

// tokens: t[b,0,:]=cls; t[b,1+p,d] = max over 32 pts of lrelu(y5*scale+shift)
__global__ void pool_kernel(const float* __restrict__ y5, const float* __restrict__ scale,
                            const float* __restrict__ shift, const float* __restrict__ cls,
                            float* __restrict__ t) {
    int gid = blockIdx.x * blockDim.x + threadIdx.x;
    if (gid >= BB * TOK * DD) return;
    int d = gid % DD; int l = (gid / DD) % TOK; int b = gid / (DD * TOK);
    float v;
    if (l == 0) {
        v = cls[d];
    } else {
        int pp = l - 1;
        const float* row = y5 + ((long)b * DD + d) * NN + pp * PSZ;
        float sc = scale[d], sh = shift[d];
        float m = -INFINITY;
        for (int i = 0; i < PSZ; ++i) {
            float u = row[i] * sc + sh;
            u = (u >= 0.f) ? u : 0.2f * u;
            m = fmaxf(m, u);
        }
        v = m;
    }
    t[gid] = v;
}

// per-token LayerNorm; if addpos: t += pos first (written back), then normalize
__global__ __launch_bounds__(256) void ln_kernel(float* __restrict__ t, const float* __restrict__ pos,
                                                 const float* __restrict__ g, const float* __restrict__ bb,
                                                 float* __restrict__ hn, int addpos) {
    __shared__ double s1[256], s2[256];
    long r = blockIdx.x;
    int tid = threadIdx.x;
    float vals[4];
    double s = 0.0, sq = 0.0;
    for (int i = 0; i < 4; ++i) {
        int d = tid + i * 256;
        float v = t[r * DD + d];
        if (addpos) { v += pos[r * DD + d]; t[r * DD + d] = v; }
        vals[i] = v; s += v; sq += (double)v * v;
    }
    s1[tid] = s; s2[tid] = sq;
    __syncthreads();
    for (int st = 128; st > 0; st >>= 1) {
        if (tid < st) { s1[tid] += s1[tid + st]; s2[tid] += s2[tid + st]; }
        __syncthreads();
    }
    double mean = s1[0] / DD;
    float var = (float)(s2[0] / DD - mean * mean);
    float fm = (float)mean;
    float inv = rsqrtf(var + EPSF);
    for (int i = 0; i < 4; ++i) {
        int d = tid + i * 256;
        hn[r * DD + d] = (vals[i] - fm) * inv * g[d] + bb[d];
    }
}

// one block per (b,h): scores -> softmax -> z
__global__ __launch_bounds__(256) void attn_kernel(const float* __restrict__ qkv, float* __restrict__ z) {
    __shared__ float ks[TOK][DHH + 1];
    __shared__ float vs[TOK][DHH + 1];
    __shared__ float ss[TOK][TOK];
    int bh = blockIdx.x;
    int b = bh / HH, h = bh % HH;
    int tid = threadIdx.x;
    for (int i = tid; i < TOK * DHH; i += 256) {
        int l = i / DHH, d = i % DHH;
        long base = (long)(b * TOK + l) * 1536;
        ks[l][d] = qkv[base + 512 + h * DHH + d];
        vs[l][d] = qkv[base + 1024 + h * DHH + d];
    }
    __syncthreads();
    for (int i = tid; i < TOK * TOK; i += 256) {
        int l = i / TOK, m = i % TOK;
        const float* qrow = qkv + (long)(b * TOK + l) * 1536 + h * DHH;
        float acc = 0.f;
        for (int d = 0; d < DHH; ++d) acc += qrow[d] * ks[m][d];
        ss[l][m] = acc * 0.125f;
    }
    __syncthreads();
    if (tid < TOK) {
        float mx = -INFINITY;
        for (int m = 0; m < TOK; ++m) mx = fmaxf(mx, ss[tid][m]);
        float sum = 0.f;
        for (int m = 0; m < TOK; ++m) { float e = expf(ss[tid][m] - mx); ss[tid][m] = e; sum += e; }
        float invs = 1.f / sum;
        for (int m = 0; m < TOK; ++m) ss[tid][m] *= invs;
    }
    __syncthreads();
    for (int i = tid; i < TOK * DHH; i += 256) {
        int l = i / DHH, d = i % DHH;
        float acc = 0.f;
        for (int m = 0; m < TOK; ++m) acc += ss[l][m] * vs[m][d];
        z[(long)(b * TOK + l) * INNER_ + h * DHH + d] = acc;
    }
}

__global__ void final_kernel(const float* __restrict__ t, float* __restrict__ out) {
    int gid = blockIdx.x * blockDim.x + threadIdx.x;
    if (gid >= BB * PP * DD) return;
    int d = gid % DD; int p = (gid / DD) % PP; int b = gid / (DD * PP);
    out[gid] = t[((long)b * TOK + 1 + p) * DD + d];
}

static inline int ceil_div(long a, long b) { return (int)((a + b - 1) / b); }

extern "C" void kernel_launch(void* const* d_in, const int* in_sizes, int n_in,
                              void* d_out, int out_size, void* d_ws, size_t ws_size,
                              hipStream_t stream) {
    const float* x    = (const float*)d_in[0];
    const float* pos  = (const float*)d_in[1];
    const float* w1   = (const float*)d_in[2];
    const float* g1   = (const float*)d_in[3];
    const float* b1   = (const float*)d_in[4];
    const float* w2   = (const float*)d_in[5];
    const float* g2   = (const float*)d_in[6];
    const float* b2   = (const float*)d_in[7];
    const float* w3   = (const float*)d_in[8];
    const float* g3   = (const float*)d_in[9];
    const float* b3   = (const float*)d_in[10];
    const float* w4   = (const float*)d_in[11];
    const float* g4   = (const float*)d_in[12];
    const float* b4   = (const float*)d_in[13];
    const float* w5   = (const float*)d_in[14];
    const float* g5   = (const float*)d_in[15];
    const float* b5   = (const float*)d_in[16];
    const float* cls  = (const float*)d_in[17];
    const float* ln1g = (const float*)d_in[18];
    const float* ln1b = (const float*)d_in[19];
    const float* wqkv = (const float*)d_in[20];
    const float* wout = (const float*)d_in[21];
    const float* bout = (const float*)d_in[22];
    const float* ln2g = (const float*)d_in[23];
    const float* ln2b = (const float*)d_in[24];
    const float* wff1 = (const float*)d_in[25];
    const float* bff1 = (const float*)d_in[26];
    const float* wff2 = (const float*)d_in[27];
    const float* bff2 = (const float*)d_in[28];
    float* out = (float*)d_out;

    // ---- workspace layout ----
    char* ws = (char*)d_ws;
    size_t off = 0;
    auto alloc = [&](size_t bytes) -> char* {
        char* ptr = ws + off;
        off = (off + bytes + 255) & ~(size_t)255;
        return ptr;
    };
    float*  h      = (float*)alloc((size_t)BB * 512 * NN * 4);
    float*  t      = (float*)alloc((size_t)BB * TOK * DD * 4);
    float*  hn     = (float*)alloc((size_t)BB * TOK * DD * 4);
    float*  qkvb   = (float*)alloc((size_t)BB * TOK * 1536 * 4);
    float*  zb     = (float*)alloc((size_t)BB * TOK * INNER_ * 4);
    float*  ub     = (float*)alloc((size_t)BB * TOK * MLPD * 4);
    double* dsum   = (double*)alloc(1024 * 8);
    double* dsq    = (double*)alloc(1024 * 8);
    float*  scaleb = (float*)alloc(1024 * 4);
    float*  shiftb = (float*)alloc(1024 * 4);
    // union region: (pts,xx,idx,p,q,dist) during edge convs, then y5 after conv4
    size_t ubase = off;
    float* y5 = (float*)(ws + ubase);                               // [B,1024,N] = 64 MB
    size_t uoff = ubase;
    auto ualloc = [&](size_t bytes) -> char* {
        char* ptr = ws + uoff;
        uoff = (uoff + bytes + 255) & ~(size_t)255;
        return ptr;
    };
    float* pts  = (float*)ualloc((size_t)BB * 3 * NN * 4);
    float* xx   = (float*)ualloc((size_t)BB * NN * 4);
    int*   idxb = (int*)  ualloc((size_t)BB * NN * KK * 4);
    float* pbuf = (float*)ualloc((size_t)BB * NN * 256 * 4);
    float* qbuf = (float*)ualloc((size_t)BB * NN * 256 * 4);
    size_t dist_off = uoff;
    float* distb = (float*)(ws + dist_off);
    size_t y5_end     = ubase + (size_t)BB * DD * NN * 4;
    size_t full_end   = dist_off + (size_t)BB * NN * NN * 4;
    size_t batch_end  = dist_off + (size_t)NN * NN * 4;
    size_t need_full  = full_end  > y5_end ? full_end  : y5_end;
    size_t need_batch = batch_end > y5_end ? batch_end : y5_end;
    bool full = ws_size >= need_full;
    if (!full && ws_size < need_batch) return;  // insufficient scratch

    // ---- stage 1: transpose points ----
    transpose_x_kernel<<<ceil_div((long)BB * NN * 3, 256), 256, 0, stream>>>(x, pts);

    // ---- stage 2: four EdgeConv blocks ----
    auto run_conv = [&](const float* xin, int xbs, int C, const float* w,
                        const float* g, const float* bb, float* hout, int O) {
        sqnorm_kernel<<<ceil_div((long)BB * NN, 256), 256, 0, stream>>>(xin, xbs, C, xx);
        if (full) {
            dist_kernel<<<dim3(NN / 64, NN / 64, BB), 256, 0, stream>>>(xin, xbs, C, xx, 0, distb);
            topk_kernel<<<dim3(NN / 4, BB), 256, 0, stream>>>(distb, 0, idxb);
        } else {
            for (int b = 0; b < BB; ++b) {
                dist_kernel<<<dim3(NN / 64, NN / 64, 1), 256, 0, stream>>>(xin, xbs, C, xx, b, distb);
                topk_kernel<<<dim3(NN / 4, 1), 256, 0, stream>>>(distb, b, idxb);
            }
        }
        {
            dim3 grid(NN / 32, O / 32, BB);
            pq_kernel<<<grid, 256, 0, stream>>>(xin, xbs, C, w, O, pbuf, qbuf);
        }
        zero_stats_kernel<<<4, 256, 0, stream>>>(dsum, dsq);
        edge_stats_kernel<<<256, 256, 0, stream>>>(pbuf, qbuf, idxb, O, dsum, dsq);
        bn_finalize_kernel<<<1, 256, 0, stream>>>(dsum, dsq, g, bb, O, (double)BB * NN * KK, scaleb, shiftb);
        edge_out_kernel<<<ceil_div((long)BB * NN * O, 256), 256, 0, stream>>>(
            pbuf, qbuf, idxb, O, scaleb, shiftb, hout, 512 * NN);
    };
    run_conv(pts, 3 * NN, 3, w1, g1, b1, h, 64);
    run_conv(h, 512 * NN, 64, w2, g2, b2, h + 64 * NN, 64);
    run_conv(h + 64 * NN, 512 * NN, 64, w3, g3, b3, h + 128 * NN, 128);
    run_conv(h + 128 * NN, 512 * NN, 128, w4, g4, b4, h + 256 * NN, 256);

    // ---- stage 3: conv5 + BN + lrelu + patch max-pool ----
    {
        dim3 grid(NN / 64, DD / 64, BB);
        gemm_kernel<<<grid, 256, 0, stream>>>(w5, h, nullptr, y5,
                                              DD, 512, NN, 0L, (long)512 * NN, (long)DD * NN, 0);
    }
    bn5_stats_kernel<<<DD, 256, 0, stream>>>(y5, g5, b5, scaleb, shiftb);
    pool_kernel<<<ceil_div((long)BB * TOK * DD, 256), 256, 0, stream>>>(y5, scaleb, shiftb, cls, t);

    // ---- stage 4: transformer ----
    const int M = BB * TOK;  // 520 rows
    for (int i = 0; i < DEPTH_; ++i) {
        ln_kernel<<<M, 256, 0, stream>>>(t, pos, ln1g + i * DD, ln1b + i * DD, hn, 1);
        {
            dim3 grid(1536 / 64, ceil_div(M, 64), 1);
            gemm_kernel<<<grid, 256, 0, stream>>>(hn, wqkv + (size_t)i * DD * 1536, nullptr, qkvb,
                                                  M, DD, 1536, 0L, 0L, 0L, 0);
        }
        attn_kernel<<<BB * HH, 256, 0, stream>>>(qkvb, zb);
        {
            dim3 grid(DD / 64, ceil_div(M, 64), 1);
            gemm_kernel<<<grid, 256, 0, stream>>>(zb, wout + (size_t)i * INNER_ * DD, bout + i * DD, t,
                                                  M, INNER_, DD, 0L, 0L, 0L, GEMM_ACC);
        }
        ln_kernel<<<M, 256, 0, stream>>>(t, nullptr, ln2g + i * DD, ln2b + i * DD, hn, 0);
        {
            dim3 grid(MLPD / 64, ceil_div(M, 64), 1);
            gemm_kernel<<<grid, 256, 0, stream>>>(hn, wff1 + (size_t)i * DD * MLPD, bff1 + i * MLPD, ub,
                                                  M, DD, MLPD, 0L, 0L, 0L, GEMM_GELU);
        }
        {
            dim3 grid(DD / 64, ceil_div(M, 64), 1);
            gemm_kernel<<<grid, 256, 0, stream>>>(ub, wff2 + (size_t)i * MLPD * DD, bff2 + i * DD, t,
                                                  M, MLPD, DD, 0L, 0L, 0L, GEMM_ACC);
        }
    }

    // ---- stage 5: output t[:,1:] ----
    final_kernel<<<ceil_div((long)BB * PP * DD, 256), 256, 0, stream>>>(t, out);
}

// Round 5
// 2441.176 us; speedup vs baseline: 4.4933x; 2.1609x over previous
//
#include <hip/hip_runtime.h>
#include <math.h>

// ---- problem constants ----
#define BB 8
#define NN 2048
#define PSZ 32
#define PP 64
#define DD 1024
#define MLPD 2048
#define DEPTH_ 6
#define HH 8
#define DHH 64
#define INNER_ 512
#define KK 20
#define TOK 65
#define EPSF 1e-5f

#define GEMM_ACC 1
#define GEMM_GELU 2
#define GEMM_OUTBF16 4

typedef __bf16 bf16_t;
typedef __attribute__((ext_vector_type(8))) __bf16 bf16x8;
typedef __attribute__((ext_vector_type(4))) float f32x4;

// x [B,N,3] -> pts [B,3,N]
__global__ void transpose_x_kernel(const float* __restrict__ x, float* __restrict__ pts) {
    int gid = blockIdx.x * blockDim.x + threadIdx.x;
    if (gid >= BB * NN * 3) return;
    int c = gid % 3; int n = (gid / 3) % NN; int b = gid / (3 * NN);
    pts[(b * 3 + c) * NN + n] = x[gid];
}

// xx[b,n] = sum_c x[b,c,n]^2
__global__ void sqnorm_kernel(const float* __restrict__ x, int bs, int C, float* __restrict__ xx) {
    int gid = blockIdx.x * blockDim.x + threadIdx.x;
    if (gid >= BB * NN) return;
    int n = gid % NN; int b = gid / NN;
    const float* xp = x + b * bs + n;
    float s = 0.f;
    for (int c = 0; c < C; ++c) { float v = xp[c * NN]; s += v * v; }
    xx[gid] = s;
}

// dist[n,m] = 2*sum_c x[c,n]x[c,m] - xx[n] - xx[m], tiled 64x64, per-batch slab in z
__global__ __launch_bounds__(256) void dist_kernel(const float* __restrict__ x, int bs, int C,
                                                   const float* __restrict__ xx, int b0,
                                                   float* __restrict__ dist) {
    __shared__ float As[16][72];
    __shared__ float Bs[16][72];
    int b = b0 + blockIdx.z;
    int n0 = blockIdx.y * 64, m0 = blockIdx.x * 64;
    int tid = threadIdx.x;
    int ty = tid / 16, tx = tid % 16;
    float acc[4][4] = {};
    const float* xb = x + (long)b * bs;
    for (int k0 = 0; k0 < C; k0 += 16) {
        for (int ppp = 0; ppp < 4; ++ppp) {
            int li = tid + ppp * 256;
            int i = li % 64, kk = li / 64;
            int c = k0 + kk;
            As[kk][i] = (c < C) ? xb[c * NN + n0 + i] : 0.f;
            Bs[kk][i] = (c < C) ? xb[c * NN + m0 + i] : 0.f;
        }
        __syncthreads();
        for (int kk = 0; kk < 16; ++kk) {
            float a[4], bv[4];
            *(float4*)a = *(const float4*)&As[kk][ty * 4];
            *(float4*)bv = *(const float4*)&Bs[kk][tx * 4];
            for (int i2 = 0; i2 < 4; ++i2)
                for (int j = 0; j < 4; ++j)
                    acc[i2][j] += a[i2] * bv[j];
        }
        __syncthreads();
    }
    float* db = dist + (long)blockIdx.z * NN * NN;
    for (int i2 = 0; i2 < 4; ++i2) {
        int n = n0 + ty * 4 + i2;
        float xn = xx[b * NN + n];
        float4 st;
        int m = m0 + tx * 4;
        st.x = 2.f * acc[i2][0] - xn - xx[b * NN + m + 0];
        st.y = 2.f * acc[i2][1] - xn - xx[b * NN + m + 1];
        st.z = 2.f * acc[i2][2] - xn - xx[b * NN + m + 2];
        st.w = 2.f * acc[i2][3] - xn - xx[b * NN + m + 3];
        *(float4*)&db[(long)n * NN + m] = st;
    }
}

// one WAVE per row: 32 vals/lane in registers, 20 butterfly-argmax rounds, no barriers.
__global__ __launch_bounds__(256) void topk_kernel(const float* __restrict__ dist, int b0,
                                                   int* __restrict__ idx) {
    int b = b0 + blockIdx.y;
    int wid = threadIdx.x >> 6, lane = threadIdx.x & 63;
    int n = blockIdx.x * 4 + wid;
    const float* row = dist + ((long)blockIdx.y * NN + n) * NN;
    float vals[32];
    #pragma unroll
    for (int s = 0; s < 32; ++s) vals[s] = row[s * 64 + lane];
    int* op = idx + ((long)b * NN + n) * KK;
    for (int kk = 0; kk < KK; ++kk) {
        float bv = vals[0]; int bsl = 0;
        #pragma unroll
        for (int s = 1; s < 32; ++s) if (vals[s] > bv) { bv = vals[s]; bsl = s; }
        int bm = bsl * 64 + lane;
        for (int off = 32; off; off >>= 1) {
            float ov = __shfl_xor(bv, off);
            int om = __shfl_xor(bm, off);
            if (ov > bv || (ov == bv && om < bm)) { bv = ov; bm = om; }
        }
        int wslot = bm >> 6, wlane = bm & 63;
        #pragma unroll
        for (int s = 0; s < 32; ++s)
            if (s == wslot) vals[s] = (lane == wlane) ? -INFINITY : vals[s];
        if (lane == 0) op[kk] = bm;
    }
}

// p/q (fp32, LDS tiled)
__global__ __launch_bounds__(256) void pq_kernel(const float* __restrict__ x, int bs, int C,
                                                 const float* __restrict__ w, int O,
                                                 float* __restrict__ p, float* __restrict__ q) {
    __shared__ float wT[256][33];
    __shared__ float xs[128][32];
    int b = blockIdx.z;
    int o0 = blockIdx.y * 32;
    int n0 = blockIdx.x * 32;
    int tid = threadIdx.x;
    for (int i = tid; i < 2 * C * 32; i += 256) {
        int c2 = i % (2 * C), o = i / (2 * C);
        wT[c2][o] = w[(o0 + o) * 2 * C + c2];
    }
    for (int i = tid; i < C * 32; i += 256) {
        int nl = i % 32, c = i / 32;
        xs[c][nl] = x[b * bs + c * NN + n0 + nl];
    }
    __syncthreads();
    int o_l = tid & 31;
    int n_base = (tid >> 5) * 4;
    float ps[4] = {0.f, 0.f, 0.f, 0.f};
    float qs[4] = {0.f, 0.f, 0.f, 0.f};
    for (int c = 0; c < C; ++c) {
        float4 xv = *(const float4*)&xs[c][n_base];
        float wa = wT[c][o_l];
        float wb = wT[C + c][o_l];
        float d = wb - wa;
        ps[0] += xv.x * wa; qs[0] += xv.x * d;
        ps[1] += xv.y * wa; qs[1] += xv.y * d;
        ps[2] += xv.z * wa; qs[2] += xv.z * d;
        ps[3] += xv.w * wa; qs[3] += xv.w * d;
    }
    for (int j = 0; j < 4; ++j) {
        long r = (long)(b * NN + n0 + n_base + j) * O + o0 + o_l;
        p[r] = ps[j];
        q[r] = qs[j];
    }
}

__global__ void zero_stats_kernel(double* __restrict__ s1, double* __restrict__ s2) {
    int t = blockIdx.x * blockDim.x + threadIdx.x;
    if (t < 1024) { s1[t] = 0.0; s2[t] = 0.0; }
}

__global__ __launch_bounds__(256) void edge_stats_kernel(const float* __restrict__ p, const float* __restrict__ q,
                                                         const int* __restrict__ idx, int O,
                                                         double* __restrict__ gsum, double* __restrict__ gsumsq) {
    int tid = threadIdx.x;
    int o = tid % O;
    int grp = tid / O;
    int ngrp = 256 / O;
    int rows_per_blk = (BB * NN) / gridDim.x;
    int r0 = blockIdx.x * rows_per_blk;
    double s = 0.0, ss = 0.0;
    for (int r = r0 + grp; r < r0 + rows_per_blk; r += ngrp) {
        int b = r / NN;
        float qv = q[r * O + o];
        for (int k = 0; k < KK; ++k) {
            int j = idx[r * KK + k];
            float v = p[(b * NN + j) * O + o] + qv;
            s += v; ss += (double)v * v;
        }
    }
    atomicAdd(&gsum[o], s);
    atomicAdd(&gsumsq[o], ss);
}

__global__ void bn_finalize_kernel(const double* __restrict__ gsum, const double* __restrict__ gsumsq,
                                   const float* __restrict__ g, const float* __restrict__ bb, int O, double cnt,
                                   float* __restrict__ scale, float* __restrict__ shift) {
    int o = blockIdx.x * blockDim.x + threadIdx.x;
    if (o >= O) return;
    double mean = gsum[o] / cnt;
    double var = gsumsq[o] / cnt - mean * mean;
    float inv = rsqrtf((float)var + EPSF);
    float sc = g[o] * inv;
    scale[o] = sc;
    shift[o] = bb[o] - (float)mean * sc;
}

__global__ void edge_out_kernel(const float* __restrict__ p, const float* __restrict__ q,
                                const int* __restrict__ idx, int O,
                                const float* __restrict__ scale, const float* __restrict__ shift,
                                float* __restrict__ out, int obs) {
    int gid = blockIdx.x * blockDim.x + threadIdx.x;
    if (gid >= BB * NN * O) return;
    int o = gid % O; int n = (gid / O) % NN; int b = gid / (O * NN);
    int r = b * NN + n;
    float qv = q[r * O + o];
    float sc = scale[o], sh = shift[o];
    float m = -INFINITY;
    for (int k = 0; k < KK; ++k) {
        int j = idx[r * KK + k];
        float v = (p[(b * NN + j) * O + o] + qv) * sc + sh;
        v = (v >= 0.f) ? v : 0.2f * v;
        m = fmaxf(m, v);
    }
    out[b * obs + o * NN + n] = m;
}

// transpose + fp32->bf16: in [R][C] -> out [C][R] bf16, batched in z
__global__ __launch_bounds__(256) void transpose_cvt_kernel(const float* __restrict__ in,
                                                            bf16_t* __restrict__ outp,
                                                            int R, int C, long s_in, long s_out) {
    __shared__ float tile[32][33];
    const float* ib = in + (long)blockIdx.z * s_in;
    bf16_t* ob = outp + (long)blockIdx.z * s_out;
    int r0 = blockIdx.y * 32, c0 = blockIdx.x * 32;
    int tx = threadIdx.x & 31, tg = threadIdx.x >> 5;
    for (int i = 0; i < 4; ++i) {
        int r = tg + i * 8;
        tile[r][tx] = ib[(long)(r0 + r) * C + c0 + tx];
    }
    __syncthreads();
    for (int i = 0; i < 4; ++i) {
        int c = tg + i * 8;
        ob[(long)(c0 + c) * R + r0 + tx] = (bf16_t)tile[tx][c];
    }
}

// bf16 MFMA GEMM: out[M,N] = A[M,K] x Bt[N,K]^T  (A fp32 cvt on stage; Bt pre-cvt bf16)
// 64x64 tile, BK=32, 4 waves each computing a 32x32 quadrant via 2x2 mfma_16x16x32.
__global__ __launch_bounds__(256) void gemm_bf16_kernel(const float* __restrict__ A,
                                                        const bf16_t* __restrict__ Bt,
                                                        const float* __restrict__ bias,
                                                        float* __restrict__ out,
                                                        int M, int Kd, int Nd,
                                                        long sA, long sBt, long sO, int flags) {
    __shared__ __align__(16) bf16_t As[64 * 32];
    __shared__ __align__(16) bf16_t Bs[64 * 32];
    const float* Ab = A + (long)blockIdx.z * sA;
    const bf16_t* Bb = Bt + (long)blockIdx.z * sBt;
    int row0 = blockIdx.y * 64, col0 = blockIdx.x * 64;
    int tid = threadIdx.x;
    int lane = tid & 63, wv = tid >> 6;
    int wm = wv >> 1, wn = wv & 1;
    int srow = tid >> 2;
    int skp = (tid & 3) * 8;
    f32x4 acc[2][2] = {};
    for (int k0 = 0; k0 < Kd; k0 += 32) {
        {
            int r = row0 + srow;
            float av[8];
            if (r < M) {
                const float* ap = Ab + (long)r * Kd + k0 + skp;
                float4 a0 = *(const float4*)ap;
                float4 a1 = *(const float4*)(ap + 4);
                av[0] = a0.x; av[1] = a0.y; av[2] = a0.z; av[3] = a0.w;
                av[4] = a1.x; av[5] = a1.y; av[6] = a1.z; av[7] = a1.w;
            } else {
                #pragma unroll
                for (int j = 0; j < 8; ++j) av[j] = 0.f;
            }
            bf16x8 v;
            #pragma unroll
            for (int j = 0; j < 8; ++j) v[j] = (bf16_t)av[j];
            *(bf16x8*)&As[((skp >> 3) * 64 + srow) * 8] = v;
        }
        {
            const bf16_t* bp = Bb + (long)(col0 + srow) * Kd + k0 + skp;
            bf16x8 v = *(const bf16x8*)bp;
            *(bf16x8*)&Bs[((skp >> 3) * 64 + srow) * 8] = v;
        }
        __syncthreads();
        int q = lane >> 4, cl = lane & 15;
        bf16x8 a0v = *(const bf16x8*)&As[(q * 64 + wm * 32 + cl) * 8];
        bf16x8 a1v = *(const bf16x8*)&As[(q * 64 + wm * 32 + 16 + cl) * 8];
        bf16x8 b0v = *(const bf16x8*)&Bs[(q * 64 + wn * 32 + cl) * 8];
        bf16x8 b1v = *(const bf16x8*)&Bs[(q * 64 + wn * 32 + 16 + cl) * 8];
        acc[0][0] = __builtin_amdgcn_mfma_f32_16x16x32_bf16(a0v, b0v, acc[0][0], 0, 0, 0);
        acc[0][1] = __builtin_amdgcn_mfma_f32_16x16x32_bf16(a0v, b1v, acc[0][1], 0, 0, 0);
        acc[1][0] = __builtin_amdgcn_mfma_f32_16x16x32_bf16(a1v, b0v, acc[1][0], 0, 0, 0);
        acc[1][1] = __builtin_amdgcn_mfma_f32_16x16x32_bf16(a1v, b1v, acc[1][1], 0, 0, 0);
        __syncthreads();
    }
    int q = lane >> 4, cl = lane & 15;
    float* Obf = out + (long)blockIdx.z * sO;
    bf16_t* Obh = (bf16_t*)out + (long)blockIdx.z * sO;
    for (int mt = 0; mt < 2; ++mt)
        for (int nt = 0; nt < 2; ++nt)
            #pragma unroll
            for (int r = 0; r < 4; ++r) {
                int row = row0 + wm * 32 + mt * 16 + q * 4 + r;
                if (row >= M) continue;
                int col = col0 + wn * 32 + nt * 16 + cl;
                float v = acc[mt][nt][r];
                if (bias) v += bias[col];
                if (flags & GEMM_GELU) v = 0.5f * v * (1.f + erff(v * 0.70710678118654752f));
                long oidx = (long)row * Nd + col;
                if (flags & GEMM_OUTBF16) Obh[oidx] = (bf16_t)v;
                else if (flags & GEMM_ACC) Obf[oidx] += v;
                else Obf[oidx] = v;
            }
}

// fp32 fallback GEMM (tight-workspace path)
__global__ __launch_bounds__(256) void gemm_kernel(const float* __restrict__ A, const float* __restrict__ Bm,
                                                   const float* __restrict__ bias, float* __restrict__ out,
                                                   int M, int Kd, int Nd, long sA, long sB, long sO, int flags) {
    __shared__ float As[16][65];
    __shared__ float Bs[16][64];
    const float* Ab = A + (long)blockIdx.z * sA;
    const float* Bb = Bm + (long)blockIdx.z * sB;
    float* Ob = out + (long)blockIdx.z * sO;
    int row0 = blockIdx.y * 64, col0 = blockIdx.x * 64;
    int tid = threadIdx.x;
    int ty = tid / 16, tx = tid % 16;
    float acc[4][4] = {};
    for (int k0 = 0; k0 < Kd; k0 += 16) {
        for (int i = 0; i < 4; ++i) {
            int li = tid + i * 256;
            int m = li / 16, kk = li % 16;
            int r = row0 + m;
            As[kk][m] = (r < M) ? Ab[(long)r * Kd + k0 + kk] : 0.f;
        }
        for (int i = 0; i < 4; ++i) {
            int li = tid + i * 256;
            int kk = li / 64, n = li % 64;
            int c = col0 + n;
            Bs[kk][n] = (c < Nd) ? Bb[(long)(k0 + kk) * Nd + c] : 0.f;
        }
        __syncthreads();
        for (int kk = 0; kk < 16; ++kk) {
            float a[4], bv[4];
            for (int i = 0; i < 4; ++i) a[i] = As[kk][ty * 4 + i];
            for (int j = 0; j < 4; ++j) bv[j] = Bs[kk][tx * 4 + j];
            for (int i = 0; i < 4; ++i)
                for (int j = 0; j < 4; ++j)
                    acc[i][j] += a[i] * bv[j];
        }
        __syncthreads();
    }
    for (int i = 0; i < 4; ++i) {
        int r = row0 + ty * 4 + i;
        if (r >= M) continue;
        for (int j = 0; j < 4; ++j) {
            int c = col0 + tx * 4 + j;
            if (c >= Nd) continue;
            float v = acc[i][j];
            if (bias) v += bias[c];
            if (flags & GEMM_GELU) v = 0.5f * v * (1.f + erff(v * 0.70710678118654752f));
            long oidx = (long)r * Nd + c;
            if (flags & GEMM_ACC) Ob[oidx] += v; else Ob[oidx] = v;
        }
    }
}

// BN5 stats over bf16 y5 [b,d,n]
__global__ __launch_bounds__(256) void bn5_stats_bf16_kernel(const bf16_t* __restrict__ y5,
                                                             const float* __restrict__ g,
                                                             const float* __restrict__ bb,
                                                             float* __restrict__ scale, float* __restrict__ shift) {
    __shared__ double ssum[256], ssq[256];
    int d = blockIdx.x;
    int tid = threadIdx.x;
    double s = 0.0, sq = 0.0;
    for (int b = 0; b < BB; ++b) {
        const bf16_t* row = y5 + ((long)b * DD + d) * NN;
        for (int n = tid; n < NN; n += 256) { float v = (float)row[n]; s += v; sq += (double)v * v; }
    }
    ssum[tid] = s; ssq[tid] = sq;
    __syncthreads();
    for (int st = 128; st > 0; st >>= 1) {
        if (tid < st) { ssum[tid] += ssum[tid + st]; ssq[tid] += ssq[tid + st]; }
        __syncthreads();
    }
    if (tid == 0) {
        double cnt = (double)BB * NN;
        double mean = ssum[0] / cnt;
        double var = ssq[0] / cnt - mean * mean;
        float inv = rsqrtf((float)var + EPSF);
        float sc = g[d] * inv;
        scale[d] = sc;
        shift[d] = bb[d] - (float)mean * sc;
    }
}

// fp32 variant (fallback path)
__global__ __launch_bounds__(256) void bn5_stats_kernel(const float* __restrict__ y5, const float* __restrict__ g,
                                                        const float* __restrict__ bb,
                                                        float* __restrict__ scale, float* __restrict__ shift) {
    __shared__ double ssum[256], ssq[256];
    int d = blockIdx.x;
    int tid = threadIdx.x;
    double s = 0.0, sq = 0.0;
    for (int b = 0; b < BB; ++b) {
        const float* row = y5 + ((long)b * DD + d) * NN;
        for (int n = tid; n < NN; n += 256) { float v = row[n]; s += v; sq += (double)v * v; }
    }
    ssum[tid] = s; ssq[tid] = sq;
    __syncthreads();
    for (int st = 128; st > 0; st >>= 1) {
        if (tid < st) { ssum[tid] += ssum[tid + st]; ssq[tid] += ssq[tid + st]; }
        __syncthreads();
    }
    if (tid == 0) {
        double cnt = (double)BB * NN;
        double mean = ssum[0] / cnt;
        double var = ssq[0] / cnt - mean * mean;
        float inv = rsqrtf((float)var + EPSF);
        float sc = g[d] * inv;
        scale[d] = sc;
        shift[d] = bb[d] - (float)mean * sc;
    }
}

// tokens from bf16 y5
__global__ void pool_bf16_kernel(const bf16_t* __restrict__ y5, const float* __restrict__ scale,
                                 const float* __restrict__ shift, const float* __restrict__ cls,
                                 float* __restrict__ t) {
    int gid = blockIdx.x * blockDim.x + threadIdx.x;
    if (gid >= BB * TOK * DD) return;
    int d = gid % DD; int l = (gid / DD) % TOK; int b = gid / (DD * TOK);
    float v;
    if (l == 0) {
        v = cls[d];
    } else {
        int pp = l - 1;
        const bf16_t* row = y5 + ((long)b * DD + d) * NN + pp * PSZ;
        float sc = scale[d], sh = shift[d];
        float m = -INFINITY;
        for (int i = 0; i < PSZ; ++i) {
            float u = (float)row[i] * sc + sh;
            u = (u >= 0.f) ? u : 0.2f * u;
            m = fmaxf(m, u);
        }
        v = m;
    }
    t[gid] = v;
}

__global__ void pool_kernel(const float* __restrict__ y5, const float* __restrict__ scale,
                            const float* __restrict__ shift, const float* __restrict__ cls,
                            float* __restrict__ t) {
    int gid = blockIdx.x * blockDim.x + threadIdx.x;
    if (gid >= BB * TOK * DD) return;
    int d = gid % DD; int l = (gid / DD) % TOK; int b = gid / (DD * TOK);
    float v;
    if (l == 0) {
        v = cls[d];
    } else {
        int pp = l - 1;
        const float* row = y5 + ((long)b * DD + d) * NN + pp * PSZ;
        float sc = scale[d], sh = shift[d];
        float m = -INFINITY;
        for (int i = 0; i < PSZ; ++i) {
            float u = row[i] * sc + sh;
            u = (u >= 0.f) ? u : 0.2f * u;
            m = fmaxf(m, u);
        }
        v = m;
    }
    t[gid] = v;
}

__global__ __launch_bounds__(256) void ln_kernel(float* __restrict__ t, const float* __restrict__ pos,
                                                 const float* __restrict__ g, const float* __restrict__ bb,
                                                 float* __restrict__ hn, int addpos) {
    __shared__ double s1[256], s2[256];
    long r = blockIdx.x;
    int tid = threadIdx.x;
    float vals[4];
    double s = 0.0, sq = 0.0;
    for (int i = 0; i < 4; ++i) {
        int d = tid + i * 256;
        float v = t[r * DD + d];
        if (addpos) { v += pos[r * DD + d]; t[r * DD + d] = v; }
        vals[i] = v; s += v; sq += (double)v * v;
    }
    s1[tid] = s; s2[tid] = sq;
    __syncthreads();
    for (int st = 128; st > 0; st >>= 1) {
        if (tid < st) { s1[tid] += s1[tid + st]; s2[tid] += s2[tid + st]; }
        __syncthreads();
    }
    double mean = s1[0] / DD;
    float var = (float)(s2[0] / DD - mean * mean);
    float fm = (float)mean;
    float inv = rsqrtf(var + EPSF);
    for (int i = 0; i < 4; ++i) {
        int d = tid + i * 256;
        hn[r * DD + d] = (vals[i] - fm) * inv * g[d] + bb[d];
    }
}

__global__ __launch_bounds__(256) void attn_kernel(const float* __restrict__ qkv, float* __restrict__ z) {
    __shared__ float ks[TOK][DHH + 1];
    __shared__ float vs[TOK][DHH + 1];
    __shared__ float ss[TOK][TOK];
    int bh = blockIdx.x;
    int b = bh / HH, h = bh % HH;
    int tid = threadIdx.x;
    for (int i = tid; i < TOK * DHH; i += 256) {
        int l = i / DHH, d = i % DHH;
        long base = (long)(b * TOK + l) * 1536;
        ks[l][d] = qkv[base + 512 + h * DHH + d];
        vs[l][d] = qkv[base + 1024 + h * DHH + d];
    }
    __syncthreads();
    for (int i = tid; i < TOK * TOK; i += 256) {
        int l = i / TOK, m = i % TOK;
        const float* qrow = qkv + (long)(b * TOK + l) * 1536 + h * DHH;
        float acc = 0.f;
        for (int d = 0; d < DHH; ++d) acc += qrow[d] * ks[m][d];
        ss[l][m] = acc * 0.125f;
    }
    __syncthreads();
    if (tid < TOK) {
        float mx = -INFINITY;
        for (int m = 0; m < TOK; ++m) mx = fmaxf(mx, ss[tid][m]);
        float sum = 0.f;
        for (int m = 0; m < TOK; ++m) { float e = expf(ss[tid][m] - mx); ss[tid][m] = e; sum += e; }
        float invs = 1.f / sum;
        for (int m = 0; m < TOK; ++m) ss[tid][m] *= invs;
    }
    __syncthreads();
    for (int i = tid; i < TOK * DHH; i += 256) {
        int l = i / DHH, d = i % DHH;
        float acc = 0.f;
        for (int m = 0; m < TOK; ++m) acc += ss[l][m] * vs[m][d];
        z[(long)(b * TOK + l) * INNER_ + h * DHH + d] = acc;
    }
}

__global__ void final_kernel(const float* __restrict__ t, float* __restrict__ out) {
    int gid = blockIdx.x * blockDim.x + threadIdx.x;
    if (gid >= BB * PP * DD) return;
    int d = gid % DD; int p = (gid / DD) % PP; int b = gid / (DD * PP);
    out[gid] = t[((long)b * TOK + 1 + p) * DD + d];
}

static inline int ceil_div(long a, long b) { return (int)((a + b - 1) / b); }

extern "C" void kernel_launch(void* const* d_in, const int* in_sizes, int n_in,
                              void* d_out, int out_size, void* d_ws, size_t ws_size,
                              hipStream_t stream) {
    const float* x    = (const float*)d_in[0];
    const float* pos  = (const float*)d_in[1];
    const float* w1   = (const float*)d_in[2];
    const float* g1   = (const float*)d_in[3];
    const float* b1   = (const float*)d_in[4];
    const float* w2   = (const float*)d_in[5];
    const float* g2   = (const float*)d_in[6];
    const float* b2   = (const float*)d_in[7];
    const float* w3   = (const float*)d_in[8];
    const float* g3   = (const float*)d_in[9];
    const float* b3   = (const float*)d_in[10];
    const float* w4   = (const float*)d_in[11];
    const float* g4   = (const float*)d_in[12];
    const float* b4   = (const float*)d_in[13];
    const float* w5   = (const float*)d_in[14];
    const float* g5   = (const float*)d_in[15];
    const float* b5   = (const float*)d_in[16];
    const float* cls  = (const float*)d_in[17];
    const float* ln1g = (const float*)d_in[18];
    const float* ln1b = (const float*)d_in[19];
    const float* wqkv = (const float*)d_in[20];
    const float* wout = (const float*)d_in[21];
    const float* bout = (const float*)d_in[22];
    const float* ln2g = (const float*)d_in[23];
    const float* ln2b = (const float*)d_in[24];
    const float* wff1 = (const float*)d_in[25];
    const float* bff1 = (const float*)d_in[26];
    const float* wff2 = (const float*)d_in[27];
    const float* bff2 = (const float*)d_in[28];
    float* out = (float*)d_out;

    // ---- workspace layout ----
    char* ws = (char*)d_ws;
    size_t off = 0;
    auto alloc = [&](size_t bytes) -> char* {
        char* ptr = ws + off;
        off = (off + bytes + 255) & ~(size_t)255;
        return ptr;
    };
    float*  h      = (float*)alloc((size_t)BB * 512 * NN * 4);   // 33.5 MB; reused as y5 BF16 (32 MB) later
    float*  t      = (float*)alloc((size_t)BB * TOK * DD * 4);
    float*  hn     = (float*)alloc((size_t)BB * TOK * DD * 4);
    float*  qkvb   = (float*)alloc((size_t)BB * TOK * 1536 * 4);
    float*  zb     = (float*)alloc((size_t)BB * TOK * INNER_ * 4);
    float*  ub     = (float*)alloc((size_t)BB * TOK * MLPD * 4);
    double* dsum   = (double*)alloc(1024 * 8);
    double* dsq    = (double*)alloc(1024 * 8);
    float*  scaleb = (float*)alloc(1024 * 4);
    float*  shiftb = (float*)alloc(1024 * 4);
    size_t ubase = off;

    // union view 1 (conv phase): pts, xx, idxb, pbuf, qbuf, dist
    size_t uoff = ubase;
    auto ualloc = [&](size_t bytes) -> char* {
        char* ptr = ws + uoff;
        uoff = (uoff + bytes + 255) & ~(size_t)255;
        return ptr;
    };
    float* pts  = (float*)ualloc((size_t)BB * 3 * NN * 4);
    float* xx   = (float*)ualloc((size_t)BB * NN * 4);
    int*   idxb = (int*)  ualloc((size_t)BB * NN * KK * 4);
    float* pbuf = (float*)ualloc((size_t)BB * NN * 256 * 4);
    float* qbuf = (float*)ualloc((size_t)BB * NN * 256 * 4);
    size_t dist_rel = uoff - ubase;
    float* distb = (float*)(ws + uoff);

    // union view 2 (stage 3/4, bf16 path): hT + transposed bf16 weights
    size_t voff = ubase;
    auto valloc = [&](size_t bytes) -> char* {
        char* ptr = ws + voff;
        voff = (voff + bytes + 255) & ~(size_t)255;
        return ptr;
    };
    bf16_t* hT     = (bf16_t*)valloc((size_t)BB * NN * 512 * 2);
    bf16_t* wTqkv  = (bf16_t*)valloc((size_t)DEPTH_ * 1536 * DD * 2);
    bf16_t* wTout  = (bf16_t*)valloc((size_t)DEPTH_ * DD * INNER_ * 2);
    bf16_t* wTff1  = (bf16_t*)valloc((size_t)DEPTH_ * MLPD * DD * 2);
    bf16_t* wTff2  = (bf16_t*)valloc((size_t)DEPTH_ * DD * MLPD * 2);
    size_t stage_bf16 = voff - ubase;   // ~92 MB (y5 lives in h as bf16 -> no extra union space)

    size_t conv_full  = dist_rel + (size_t)BB * NN * NN * 4;
    size_t conv_batch = dist_rel + (size_t)NN * NN * 4;
    size_t stage_fp32 = (size_t)BB * DD * NN * 4;   // y5 fp32 in union (fallback)

    auto mx = [](size_t a, size_t b) { return a > b ? a : b; };
    bool use_bf16 = ws_size >= ubase + mx(conv_batch, stage_bf16);
    bool full     = ws_size >= ubase + mx(conv_full, use_bf16 ? stage_bf16 : stage_fp32);
    if (!use_bf16 && ws_size < ubase + mx(conv_batch, stage_fp32)) return;  // insufficient scratch
    bf16_t* y5bf = (bf16_t*)h;                           // 32 MB fits in h's 33.5 MB slot
    float*  y5f  = (float*)(ws + ubase);                 // fallback fp32 y5

    // ---- stage 1: transpose points ----
    transpose_x_kernel<<<ceil_div((long)BB * NN * 3, 256), 256, 0, stream>>>(x, pts);

    // ---- stage 2: four EdgeConv blocks ----
    auto run_conv = [&](const float* xin, int xbs, int C, const float* w,
                        const float* g, const float* bb, float* hout, int O) {
        sqnorm_kernel<<<ceil_div((long)BB * NN, 256), 256, 0, stream>>>(xin, xbs, C, xx);
        if (full) {
            dist_kernel<<<dim3(NN / 64, NN / 64, BB), 256, 0, stream>>>(xin, xbs, C, xx, 0, distb);
            topk_kernel<<<dim3(NN / 4, BB), 256, 0, stream>>>(distb, 0, idxb);
        } else {
            for (int b = 0; b < BB; ++b) {
                dist_kernel<<<dim3(NN / 64, NN / 64, 1), 256, 0, stream>>>(xin, xbs, C, xx, b, distb);
                topk_kernel<<<dim3(NN / 4, 1), 256, 0, stream>>>(distb, b, idxb);
            }
        }
        {
            dim3 grid(NN / 32, O / 32, BB);
            pq_kernel<<<grid, 256, 0, stream>>>(xin, xbs, C, w, O, pbuf, qbuf);
        }
        zero_stats_kernel<<<4, 256, 0, stream>>>(dsum, dsq);
        edge_stats_kernel<<<256, 256, 0, stream>>>(pbuf, qbuf, idxb, O, dsum, dsq);
        bn_finalize_kernel<<<1, 256, 0, stream>>>(dsum, dsq, g, bb, O, (double)BB * NN * KK, scaleb, shiftb);
        edge_out_kernel<<<ceil_div((long)BB * NN * O, 256), 256, 0, stream>>>(
            pbuf, qbuf, idxb, O, scaleb, shiftb, hout, 512 * NN);
    };
    run_conv(pts, 3 * NN, 3, w1, g1, b1, h, 64);
    run_conv(h, 512 * NN, 64, w2, g2, b2, h + 64 * NN, 64);
    run_conv(h + 64 * NN, 512 * NN, 64, w3, g3, b3, h + 128 * NN, 128);
    run_conv(h + 128 * NN, 512 * NN, 128, w4, g4, b4, h + 256 * NN, 256);

    const int M = BB * TOK;  // 520 rows
    if (use_bf16) {
        // ---- transposes: h -> hT (bf16), weights -> [N][K] bf16 ----
        transpose_cvt_kernel<<<dim3(NN / 32, 512 / 32, BB), 256, 0, stream>>>(
            h, hT, 512, NN, (long)512 * NN, (long)NN * 512);
        transpose_cvt_kernel<<<dim3(1536 / 32, DD / 32, DEPTH_), 256, 0, stream>>>(
            wqkv, wTqkv, DD, 1536, (long)DD * 1536, (long)1536 * DD);
        transpose_cvt_kernel<<<dim3(DD / 32, INNER_ / 32, DEPTH_), 256, 0, stream>>>(
            wout, wTout, INNER_, DD, (long)INNER_ * DD, (long)DD * INNER_);
        transpose_cvt_kernel<<<dim3(MLPD / 32, DD / 32, DEPTH_), 256, 0, stream>>>(
            wff1, wTff1, DD, MLPD, (long)DD * MLPD, (long)MLPD * DD);
        transpose_cvt_kernel<<<dim3(DD / 32, MLPD / 32, DEPTH_), 256, 0, stream>>>(
            wff2, wTff2, MLPD, DD, (long)MLPD * DD, (long)DD * MLPD);

        // ---- stage 3: conv5 (MFMA, bf16 out into h's slot) + BN + pool ----
        gemm_bf16_kernel<<<dim3(NN / 64, DD / 64, BB), 256, 0, stream>>>(
            w5, hT, nullptr, (float*)y5bf, DD, 512, NN, 0L, (long)NN * 512, (long)DD * NN, GEMM_OUTBF16);
        bn5_stats_bf16_kernel<<<DD, 256, 0, stream>>>(y5bf, g5, b5, scaleb, shiftb);
        pool_bf16_kernel<<<ceil_div((long)BB * TOK * DD, 256), 256, 0, stream>>>(y5bf, scaleb, shiftb, cls, t);

        // ---- stage 4: transformer (MFMA GEMMs) ----
        for (int i = 0; i < DEPTH_; ++i) {
            ln_kernel<<<M, 256, 0, stream>>>(t, pos, ln1g + i * DD, ln1b + i * DD, hn, 1);
            gemm_bf16_kernel<<<dim3(1536 / 64, ceil_div(M, 64), 1), 256, 0, stream>>>(
                hn, wTqkv + (size_t)i * 1536 * DD, nullptr, qkvb, M, DD, 1536, 0L, 0L, 0L, 0);
            attn_kernel<<<BB * HH, 256, 0, stream>>>(qkvb, zb);
            gemm_bf16_kernel<<<dim3(DD / 64, ceil_div(M, 64), 1), 256, 0, stream>>>(
                zb, wTout + (size_t)i * DD * INNER_, bout + i * DD, t, M, INNER_, DD, 0L, 0L, 0L, GEMM_ACC);
            ln_kernel<<<M, 256, 0, stream>>>(t, nullptr, ln2g + i * DD, ln2b + i * DD, hn, 0);
            gemm_bf16_kernel<<<dim3(MLPD / 64, ceil_div(M, 64), 1), 256, 0, stream>>>(
                hn, wTff1 + (size_t)i * MLPD * DD, bff1 + i * MLPD, ub, M, DD, MLPD, 0L, 0L, 0L, GEMM_GELU);
            gemm_bf16_kernel<<<dim3(DD / 64, ceil_div(M, 64), 1), 256, 0, stream>>>(
                ub, wTff2 + (size_t)i * DD * MLPD, bff2 + i * DD, t, M, MLPD, DD, 0L, 0L, 0L, GEMM_ACC);
        }
    } else {
        // ---- fp32 fallback path ----
        gemm_kernel<<<dim3(NN / 64, DD / 64, BB), 256, 0, stream>>>(
            w5, h, nullptr, y5f, DD, 512, NN, 0L, (long)512 * NN, (long)DD * NN, 0);
        bn5_stats_kernel<<<DD, 256, 0, stream>>>(y5f, g5, b5, scaleb, shiftb);
        pool_kernel<<<ceil_div((long)BB * TOK * DD, 256), 256, 0, stream>>>(y5f, scaleb, shiftb, cls, t);
        for (int i = 0; i < DEPTH_; ++i) {
            ln_kernel<<<M, 256, 0, stream>>>(t, pos, ln1g + i * DD, ln1b + i * DD, hn, 1);
            gemm_kernel<<<dim3(1536 / 64, ceil_div(M, 64), 1), 256, 0, stream>>>(
                hn, wqkv + (size_t)i * DD * 1536, nullptr, qkvb, M, DD, 1536, 0L, 0L, 0L, 0);
            attn_kernel<<<BB * HH, 256, 0, stream>>>(qkvb, zb);
            gemm_kernel<<<dim3(DD / 64, ceil_div(M, 64), 1), 256, 0, stream>>>(
                zb, wout + (size_t)i * INNER_ * DD, bout + i * DD, t, M, INNER_, DD, 0L, 0L, 0L, GEMM_ACC);
            ln_kernel<<<M, 256, 0, stream>>>(t, nullptr, ln2g + i * DD, ln2b + i * DD, hn, 0);
            gemm_kernel<<<dim3(MLPD / 64, ceil_div(M, 64), 1), 256, 0, stream>>>(
                hn, wff1 + (size_t)i * DD * MLPD, bff1 + i * MLPD, ub, M, DD, MLPD, 0L, 0L, 0L, GEMM_GELU);
            gemm_kernel<<<dim3(DD / 64, ceil_div(M, 64), 1), 256, 0, stream>>>(
                ub, wff2 + (size_t)i * MLPD * DD, bff2 + i * DD, t, M, MLPD, DD, 0L, 0L, 0L, GEMM_ACC);
        }
    }

    // ---- stage 5: output t[:,1:] ----
    final_kernel<<<ceil_div((long)BB * PP * DD, 256), 256, 0, stream>>>(t, out);
}